// Round 4
// baseline (426.904 us; speedup 1.0000x reference)
//
#include <hip/hip_runtime.h>
#include <hip/hip_bf16.h>

#define DEV __device__ __forceinline__

typedef __attribute__((ext_vector_type(8))) short bf16x8;
typedef __attribute__((ext_vector_type(4))) float f32x4;

DEV float b2f(unsigned short u) {
    unsigned int v = ((unsigned int)u) << 16;
    float f; __builtin_memcpy(&f, &v, 4); return f;
}
DEV unsigned short f2b(float f) {            // RNE via bit-ops
    unsigned int v; __builtin_memcpy(&v, &f, 4);
    v = (v + 0x7fffu + ((v >> 16) & 1u)) >> 16;
    return (unsigned short)v;
}
DEV unsigned short f2b_hw(float f) {         // hardware cvt (RNE)
    __hip_bfloat16 h = __float2bfloat16(f);
    unsigned short u; __builtin_memcpy(&u, &h, 2); return u;
}

DEV f32x4 mfma16(bf16x8 a, bf16x8 b, f32x4 c) {
    return __builtin_amdgcn_mfma_f32_16x16x32_bf16(a, b, c, 0, 0, 0);
}

constexpr float SCALE_L2E = 0.125f * 1.44269504088896340736f;  // DH^-0.5 * log2(e)

// ---------------------------------------------------------------------------
// K0: fp32 -> bf16 conversions.
//  xb[4096][512]  = x
//  wt[1664][512]  = [wq_s | wk_s | wv_r | wq_r]^T  (B^T form for MFMA)
//  wot[512][512]  = w_out^T
//  wkt[64][64]    = wk_ret ROW-MAJOR (B^T form for T = RQ @ wk_ret^T:
//                   B^T[j][k] must equal wk_ret[j][k] — no transpose!)
// ---------------------------------------------------------------------------
__global__ void k_convert(const float* __restrict__ x,
                          const float* __restrict__ wq_s, const float* __restrict__ wk_s,
                          const float* __restrict__ wv_r, const float* __restrict__ wq_r,
                          const float* __restrict__ wk_ret, const float* __restrict__ w_out,
                          unsigned short* __restrict__ xb,
                          unsigned short* __restrict__ wt,
                          unsigned short* __restrict__ wot,
                          unsigned short* __restrict__ wkt)
{
    const int T1 = 4096 * 512;
    const int T2 = 1664 * 512;
    const int T3 = 512 * 512;
    const int T4 = 64 * 64;
    const int total = T1 + T2 + T3 + T4;
    for (int idx = blockIdx.x * blockDim.x + threadIdx.x; idx < total;
         idx += gridDim.x * blockDim.x) {
        if (idx < T1) {
            xb[idx] = f2b(x[idx]);
        } else if (idx < T1 + T2) {
            int t = idx - T1;
            int n = t >> 9, k = t & 511;   // t == n*512 + k
            float v;
            if (n < 512)       v = wq_s[k * 512 + n];
            else if (n < 1024) v = wk_s[k * 512 + (n - 512)];
            else if (n < 1152) v = wv_r[k * 128 + (n - 1024)];
            else               v = wq_r[k * 512 + (n - 1152)];
            wt[t] = f2b(v);
        } else if (idx < T1 + T2 + T3) {
            int t = idx - T1 - T2;
            int n = t >> 9, k = t & 511;
            wot[t] = f2b(w_out[k * 512 + n]);
        } else {
            int t = idx - T1 - T2 - T3;
            wkt[t] = f2b(wk_ret[t]);       // identity copy (see header comment)
        }
    }
}

// ---------------------------------------------------------------------------
// K1: projection GEMM  C[4096][1664] = xb @ wt^T, epilogue scatters into
//     qs/ks/rqb  (bf16[b][s][n][64], q's pre-scaled by DH^-0.5 * log2e)
//     and vt (bf16[b][128][n], transposed V).
// grid (64, 26), 256 threads (4 waves x 16 rows, 64 cols/block)
// ---------------------------------------------------------------------------
__global__ __launch_bounds__(256) void k_proj(const unsigned short* __restrict__ xb,
                                              const unsigned short* __restrict__ wt,
                                              unsigned short* __restrict__ qs,
                                              unsigned short* __restrict__ ks,
                                              unsigned short* __restrict__ rqb,
                                              unsigned short* __restrict__ vt)
{
    const int lane = threadIdx.x & 63, wid = threadIdx.x >> 6;
    const int lr = lane & 15, lg = lane >> 4;
    const int row0 = blockIdx.x * 64 + wid * 16;
    const int col0 = blockIdx.y * 64;

    const f32x4 z = {0.f, 0.f, 0.f, 0.f};
    f32x4 acc[4];
#pragma unroll
    for (int ct = 0; ct < 4; ++ct) acc[ct] = z;

    const unsigned short* ap = xb + (row0 + lr) * 512 + lg * 8;
#pragma unroll 4
    for (int k0 = 0; k0 < 512; k0 += 32) {
        bf16x8 a = *(const bf16x8*)(ap + k0);
#pragma unroll
        for (int ct = 0; ct < 4; ++ct) {
            bf16x8 b = *(const bf16x8*)(wt + (col0 + ct * 16 + lr) * 512 + k0 + lg * 8);
            acc[ct] = mfma16(a, b, acc[ct]);
        }
    }

#pragma unroll
    for (int ct = 0; ct < 4; ++ct) {
#pragma unroll
        for (int i = 0; i < 4; ++i) {
            int gr = row0 + lg * 4 + i;          // 0..4095
            int gc = col0 + ct * 16 + lr;        // 0..1663
            float v = acc[ct][i];
            int b = gr >> 11, in = gr & 2047;
            if (gc < 512) {
                int s = gc >> 6, d = gc & 63;
                qs[((b * 8 + s) * 2048 + in) * 64 + d] = f2b(v * SCALE_L2E);
            } else if (gc < 1024) {
                int c = gc - 512; int s = c >> 6, d = c & 63;
                ks[((b * 8 + s) * 2048 + in) * 64 + d] = f2b(v);
            } else if (gc < 1152) {
                int c = gc - 1024;               // 0..127 = r*64+d
                vt[(b * 128 + c) * 2048 + in] = f2b(v);
            } else {
                int c = gc - 1152; int s = c >> 6, d = c & 63;
                rqb[((b * 8 + s) * 2048 + in) * 64 + d] = f2b(v * SCALE_L2E);
            }
        }
    }
}

// ---------------------------------------------------------------------------
// K2: flash attention (stage 1) + fused retrieval composition (stage 2).
// In-block split-KV: grid 1024 = (b*s)[16] x qtile32[64]; 4 waves:
//   wave w: q-rows (w&1)*16..+16, kv-half h=w>>1 (keys h*1024..h*1024+1024).
// Halves h=1 dump fp32 partials (acc,m,l) to LDS; one barrier; h=0 waves do
// the flash merge and the fused stage-2 epilogue (T = RQ@wk_ret^T via MFMA,
// softmax over r=2, combine) -> ob bf16.
// ---------------------------------------------------------------------------
__global__ __launch_bounds__(256, 4) void k_attn(const unsigned short* __restrict__ qs,
                                                 const unsigned short* __restrict__ ks,
                                                 const unsigned short* __restrict__ rqb,
                                                 const unsigned short* __restrict__ vt,
                                                 const unsigned short* __restrict__ wkt,
                                                 unsigned short* __restrict__ ob)
{
    __shared__ unsigned short p_lds[4][16][72];       // 9.2 KB (pad 64->72)
    __shared__ float mrg[2][16][132];                 // 16.9 KB (pad 128->132)
    __shared__ float ml[2][16][2];                    // 256 B

    const int tid = threadIdx.x;
    const int lane = tid & 63, wid = tid >> 6;
    const int lr = lane & 15, lg = lane >> 4;
    const int bid = blockIdx.x;
    const int bs = bid >> 6, qt = bid & 63;           // bs = b*8+s
    const int gb = bs >> 3, gs = bs & 7;
    const int qrow0 = qt * 32 + (wid & 1) * 16;
    const int h = wid >> 1;                           // kv half

    // Q fragments, kept in registers for the whole main loop
    const unsigned short* qbase = qs + ((size_t)bs * 2048 + qrow0 + lr) * 64 + lg * 8;
    const bf16x8 q0 = *(const bf16x8*)(qbase);
    const bf16x8 q1 = *(const bf16x8*)(qbase + 32);

    const unsigned short* kpl = ks + (size_t)bs * 131072 + h * 65536 + lr * 64 + lg * 8;
    const unsigned short* vpl = vt + (size_t)gb * 262144 + lr * 2048 + h * 1024 + lg * 8;

    const f32x4 z = {0.f, 0.f, 0.f, 0.f};
    bf16x8 ones;
#pragma unroll
    for (int j = 0; j < 8; ++j) ones[j] = (short)0x3F80;

    float m_r[4];
    f32x4 acc[8];
    f32x4 acc_l = z;
#pragma unroll
    for (int i = 0; i < 4; ++i) m_r[i] = -3.0e38f;
#pragma unroll
    for (int c8 = 0; c8 < 8; ++c8) acc[c8] = z;

    // preload K frags for tile 0
    bf16x8 kf[8];
#pragma unroll
    for (int ct = 0; ct < 4; ++ct)
#pragma unroll
        for (int ksb = 0; ksb < 2; ++ksb)
            kf[ct * 2 + ksb] = *(const bf16x8*)(kpl + ct * 1024 + ksb * 32);

    for (int kt = 0; kt < 16; ++kt) {
        const int k0 = kt * 64;
        // --- issue V loads for this tile (16 x 16B); consumed after softmax
        bf16x8 vf[16];
#pragma unroll
        for (int c8 = 0; c8 < 8; ++c8)
#pragma unroll
            for (int ksb = 0; ksb < 2; ++ksb)
                vf[c8 * 2 + ksb] = *(const bf16x8*)(vpl + c8 * 32768 + k0 + ksb * 32);

        // --- S = Q K^T (16 x 64 tile), 4 col-tiles of 16
        f32x4 s[4];
#pragma unroll
        for (int ct = 0; ct < 4; ++ct) {
            f32x4 t = z;
            t = mfma16(q0, kf[ct * 2 + 0], t);
            t = mfma16(q1, kf[ct * 2 + 1], t);
            s[ct] = t;
        }

        // --- prefetch K frags for next tile
        bf16x8 kn[8];
        if (kt != 15) {
#pragma unroll
            for (int ct = 0; ct < 4; ++ct)
#pragma unroll
                for (int ksb = 0; ksb < 2; ++ksb)
                    kn[ct * 2 + ksb] = *(const bf16x8*)(kpl + (k0 + 64) * 64 + ct * 1024 + ksb * 32);
        }

        // --- deferred-max online softmax (all values in log2 units)
        float lm[4];
        bool need = false;
#pragma unroll
        for (int i = 0; i < 4; ++i) {
            lm[i] = fmaxf(fmaxf(s[0][i], s[1][i]), fmaxf(s[2][i], s[3][i]));
            need = need || (lm[i] > m_r[i] + 8.0f);
        }
        if (__any(need)) {
#pragma unroll
            for (int i = 0; i < 4; ++i) {
                float mx = lm[i];
                mx = fmaxf(mx, __shfl_xor(mx, 1, 16));
                mx = fmaxf(mx, __shfl_xor(mx, 2, 16));
                mx = fmaxf(mx, __shfl_xor(mx, 4, 16));
                mx = fmaxf(mx, __shfl_xor(mx, 8, 16));
                float m_new = fmaxf(m_r[i], mx);
                float alpha = exp2f(m_r[i] - m_new);
#pragma unroll
                for (int c8 = 0; c8 < 8; ++c8) acc[c8][i] *= alpha;
                acc_l[i] *= alpha;
                m_r[i] = m_new;
            }
        }
        // --- P = exp2(S - m), bf16, through wave-private LDS tile
#pragma unroll
        for (int i = 0; i < 4; ++i) {
#pragma unroll
            for (int ct = 0; ct < 4; ++ct)
                p_lds[wid][lg * 4 + i][ct * 16 + lr] = f2b_hw(exp2f(s[ct][i] - m_r[i]));
        }
        bf16x8 pf0 = *(const bf16x8*)(&p_lds[wid][lr][lg * 8]);
        bf16x8 pf1 = *(const bf16x8*)(&p_lds[wid][lr][32 + lg * 8]);

        // --- PV (+ row-sum into acc_l via ones-column)
#pragma unroll
        for (int c8 = 0; c8 < 8; ++c8) {
            acc[c8] = mfma16(pf0, vf[c8 * 2 + 0], acc[c8]);
            acc[c8] = mfma16(pf1, vf[c8 * 2 + 1], acc[c8]);
        }
        acc_l = mfma16(pf0, ones, acc_l);
        acc_l = mfma16(pf1, ones, acc_l);

        if (kt != 15) {
#pragma unroll
            for (int j = 0; j < 8; ++j) kf[j] = kn[j];
        }
    }

    // --- split-KV merge through LDS: h=1 waves publish fp32 partials
    if (h == 1) {
#pragma unroll
        for (int c8 = 0; c8 < 8; ++c8)
#pragma unroll
            for (int i = 0; i < 4; ++i)
                mrg[wid & 1][lg * 4 + i][c8 * 16 + lr] = acc[c8][i];
        if (lr == 0) {
#pragma unroll
            for (int i = 0; i < 4; ++i) {
                ml[wid & 1][lg * 4 + i][0] = m_r[i];
                ml[wid & 1][lg * 4 + i][1] = acc_l[i];
            }
        }
    }
    __syncthreads();
    if (h == 1) return;

    const int slot = wid & 1;

    // rq fragments (pre-scaled by DH^-0.5*log2e in k_proj)
    const unsigned short* rqbase = rqb + ((size_t)bs * 2048 + qrow0 + lr) * 64 + lg * 8;
    const bf16x8 rq0 = *(const bf16x8*)(rqbase);
    const bf16x8 rq1 = *(const bf16x8*)(rqbase + 32);

    // merge partner partials
    float inv[4];
    f32x4 accM[8];
#pragma unroll
    for (int i = 0; i < 4; ++i) {
        float m_b = ml[slot][lg * 4 + i][0];
        float l_b = ml[slot][lg * 4 + i][1];
        float m_new = fmaxf(m_r[i], m_b);
        float fa = exp2f(m_r[i] - m_new);
        float fb = exp2f(m_b - m_new);
        inv[i] = 1.0f / (acc_l[i] * fa + l_b * fb);
#pragma unroll
        for (int c8 = 0; c8 < 8; ++c8)
            accM[c8][i] = acc[c8][i] * fa + mrg[slot][lg * 4 + i][c8 * 16 + lr] * fb;
    }

    // --- stage 2 via MFMA: T[q][d] = sum_dp rq[q][dp] * wk_ret[d][dp]
    f32x4 Tt[4];
#pragma unroll
    for (int ct = 0; ct < 4; ++ct) {
        bf16x8 wb0 = *(const bf16x8*)(wkt + (ct * 16 + lr) * 64 + lg * 8);
        bf16x8 wb1 = *(const bf16x8*)(wkt + (ct * 16 + lr) * 64 + 32 + lg * 8);
        f32x4 t = z;
        t = mfma16(rq0, wb0, t);
        t = mfma16(rq1, wb1, t);
        Tt[ct] = t;
    }

    // sim_r[row] = sum_{d} T[row][d] * retrN[row][r*64+d]   (log2 units)
    float w0v[4], w1v[4];
#pragma unroll
    for (int i = 0; i < 4; ++i) {
        float s0 = 0.f, s1 = 0.f;
#pragma unroll
        for (int ct = 0; ct < 4; ++ct) {
            s0 += Tt[ct][i] * accM[ct][i];
            s1 += Tt[ct][i] * accM[4 + ct][i];
        }
        s0 *= inv[i]; s1 *= inv[i];
        s0 += __shfl_xor(s0, 1, 16); s1 += __shfl_xor(s1, 1, 16);
        s0 += __shfl_xor(s0, 2, 16); s1 += __shfl_xor(s1, 2, 16);
        s0 += __shfl_xor(s0, 4, 16); s1 += __shfl_xor(s1, 4, 16);
        s0 += __shfl_xor(s0, 8, 16); s1 += __shfl_xor(s1, 8, 16);
        float mm = fmaxf(s0, s1);
        float e0 = exp2f(s0 - mm), e1 = exp2f(s1 - mm);
        float inw = 1.0f / (e0 + e1);
        w0v[i] = e0 * inw; w1v[i] = e1 * inw;
    }

    // --- combine r=2 and store ob[b][n][gs*64 + d]
#pragma unroll
    for (int ct = 0; ct < 4; ++ct) {
#pragma unroll
        for (int i = 0; i < 4; ++i) {
            float o = (w0v[i] * accM[ct][i] + w1v[i] * accM[4 + ct][i]) * inv[i];
            ob[((size_t)gb * 2048 + qrow0 + lg * 4 + i) * 512 + gs * 64 + ct * 16 + lr] = f2b_hw(o);
        }
    }
}

// ---------------------------------------------------------------------------
// K3: final GEMM  out[4096][512] (fp32) = ob(bf16) @ w_out, via wot = w_out^T
// grid (64, 8), 256 threads
// ---------------------------------------------------------------------------
__global__ __launch_bounds__(256) void k_out(const unsigned short* __restrict__ ob,
                                             const unsigned short* __restrict__ wot,
                                             float* __restrict__ out)
{
    const int lane = threadIdx.x & 63, wid = threadIdx.x >> 6;
    const int lr = lane & 15, lg = lane >> 4;
    const int row0 = blockIdx.x * 64 + wid * 16;
    const int col0 = blockIdx.y * 64;

    const f32x4 z = {0.f, 0.f, 0.f, 0.f};
    f32x4 acc[4];
#pragma unroll
    for (int ct = 0; ct < 4; ++ct) acc[ct] = z;

    const unsigned short* ap = ob + (row0 + lr) * 512 + lg * 8;
#pragma unroll 4
    for (int k0 = 0; k0 < 512; k0 += 32) {
        bf16x8 a = *(const bf16x8*)(ap + k0);
#pragma unroll
        for (int ct = 0; ct < 4; ++ct) {
            bf16x8 b = *(const bf16x8*)(wot + (col0 + ct * 16 + lr) * 512 + k0 + lg * 8);
            acc[ct] = mfma16(a, b, acc[ct]);
        }
    }
#pragma unroll
    for (int ct = 0; ct < 4; ++ct)
#pragma unroll
        for (int i = 0; i < 4; ++i)
            out[(size_t)(row0 + lg * 4 + i) * 512 + col0 + ct * 16 + lr] = acc[ct][i];
}

// ---------------------------------------------------------------------------
extern "C" void kernel_launch(void* const* d_in, const int* in_sizes, int n_in,
                              void* d_out, int out_size, void* d_ws, size_t ws_size,
                              hipStream_t stream)
{
    (void)in_sizes; (void)n_in; (void)out_size; (void)ws_size;
    const float* x      = (const float*)d_in[0];
    const float* wq_s   = (const float*)d_in[1];
    const float* wk_s   = (const float*)d_in[2];
    const float* wv_r   = (const float*)d_in[3];
    const float* wq_r   = (const float*)d_in[4];
    const float* wk_ret = (const float*)d_in[5];
    const float* w_out  = (const float*)d_in[6];

    char* ws = (char*)d_ws;                            // needs ~24.3 MB
    unsigned short* xb  = (unsigned short*)(ws + 0);          // [4096][512]
    unsigned short* wt  = (unsigned short*)(ws + 4194304);    // [1664][512]
    unsigned short* qsb = (unsigned short*)(ws + 5898240);    // [2][8][2048][64]
    unsigned short* ksb = (unsigned short*)(ws + 10092544);   // [2][8][2048][64]
    unsigned short* rqb = (unsigned short*)(ws + 14286848);   // [2][8][2048][64]
    unsigned short* vtb = (unsigned short*)(ws + 18481152);   // [2][128][2048]
    unsigned short* obb = (unsigned short*)(ws + 19529728);   // [2][2048][512]
    unsigned short* wot = (unsigned short*)(ws + 23724032);   // [512][512]
    unsigned short* wkt = (unsigned short*)(ws + 24248320);   // [64][64]

    hipLaunchKernelGGL(k_convert, dim3(2048), dim3(256), 0, stream,
                       x, wq_s, wk_s, wv_r, wq_r, wk_ret, w_out, xb, wt, wot, wkt);
    hipLaunchKernelGGL(k_proj, dim3(64, 26), dim3(256), 0, stream,
                       xb, wt, qsb, ksb, rqb, vtb);
    hipLaunchKernelGGL(k_attn, dim3(1024), dim3(256), 0, stream,
                       qsb, ksb, rqb, vtb, wkt, obb);
    hipLaunchKernelGGL(k_out, dim3(64, 8), dim3(256), 0, stream,
                       obb, wot, (float*)d_out);
}

// Round 5
// 274.452 us; speedup vs baseline: 1.5555x; 1.5555x over previous
//
#include <hip/hip_runtime.h>
#include <hip/hip_bf16.h>

#define DEV __device__ __forceinline__

typedef __attribute__((ext_vector_type(8))) short bf16x8;
typedef __attribute__((ext_vector_type(4))) float f32x4;

DEV float b2f(unsigned short u) {
    unsigned int v = ((unsigned int)u) << 16;
    float f; __builtin_memcpy(&f, &v, 4); return f;
}
DEV unsigned short f2b(float f) {            // RNE via bit-ops
    unsigned int v; __builtin_memcpy(&v, &f, 4);
    v = (v + 0x7fffu + ((v >> 16) & 1u)) >> 16;
    return (unsigned short)v;
}
DEV unsigned short f2b_hw(float f) {         // hardware cvt (RNE)
    __hip_bfloat16 h = __float2bfloat16(f);
    unsigned short u; __builtin_memcpy(&u, &h, 2); return u;
}

DEV f32x4 mfma16(bf16x8 a, bf16x8 b, f32x4 c) {
    return __builtin_amdgcn_mfma_f32_16x16x32_bf16(a, b, c, 0, 0, 0);
}

constexpr float SCALE_L2E = 0.125f * 1.44269504088896340736f;  // DH^-0.5 * log2(e)

// ---------------------------------------------------------------------------
// K0: fp32 -> bf16 conversions.
//  xb[4096][512]  = x
//  wt[1664][512]  = [wq_s | wk_s | wv_r | wq_r]^T  (B^T form for MFMA)
//  wot[512][512]  = w_out^T
//  wkt[64][64]    = wk_ret ROW-MAJOR (B^T form for T = RQ @ wk_ret^T)
// ---------------------------------------------------------------------------
__global__ void k_convert(const float* __restrict__ x,
                          const float* __restrict__ wq_s, const float* __restrict__ wk_s,
                          const float* __restrict__ wv_r, const float* __restrict__ wq_r,
                          const float* __restrict__ wk_ret, const float* __restrict__ w_out,
                          unsigned short* __restrict__ xb,
                          unsigned short* __restrict__ wt,
                          unsigned short* __restrict__ wot,
                          unsigned short* __restrict__ wkt)
{
    const int T1 = 4096 * 512;
    const int T2 = 1664 * 512;
    const int T3 = 512 * 512;
    const int T4 = 64 * 64;
    const int total = T1 + T2 + T3 + T4;
    for (int idx = blockIdx.x * blockDim.x + threadIdx.x; idx < total;
         idx += gridDim.x * blockDim.x) {
        if (idx < T1) {
            xb[idx] = f2b(x[idx]);
        } else if (idx < T1 + T2) {
            int t = idx - T1;
            int n = t >> 9, k = t & 511;   // t == n*512 + k
            float v;
            if (n < 512)       v = wq_s[k * 512 + n];
            else if (n < 1024) v = wk_s[k * 512 + (n - 512)];
            else if (n < 1152) v = wv_r[k * 128 + (n - 1024)];
            else               v = wq_r[k * 512 + (n - 1152)];
            wt[t] = f2b(v);
        } else if (idx < T1 + T2 + T3) {
            int t = idx - T1 - T2;
            int n = t >> 9, k = t & 511;
            wot[t] = f2b(w_out[k * 512 + n]);
        } else {
            int t = idx - T1 - T2 - T3;
            wkt[t] = f2b(wk_ret[t]);       // identity copy (row-major B^T)
        }
    }
}

// ---------------------------------------------------------------------------
// K1: projection GEMM  C[4096][1664] = xb @ wt^T, epilogue scatters into
//     qs/ks/rqb  (bf16[b][s][n][64], q's pre-scaled by DH^-0.5 * log2e)
//     and vt (bf16[b][128][n], transposed V).
// grid (64, 26), 256 threads (4 waves x 16 rows, 64 cols/block)
// ---------------------------------------------------------------------------
__global__ __launch_bounds__(256) void k_proj(const unsigned short* __restrict__ xb,
                                              const unsigned short* __restrict__ wt,
                                              unsigned short* __restrict__ qs,
                                              unsigned short* __restrict__ ks,
                                              unsigned short* __restrict__ rqb,
                                              unsigned short* __restrict__ vt)
{
    const int lane = threadIdx.x & 63, wid = threadIdx.x >> 6;
    const int lr = lane & 15, lg = lane >> 4;
    const int row0 = blockIdx.x * 64 + wid * 16;
    const int col0 = blockIdx.y * 64;

    const f32x4 z = {0.f, 0.f, 0.f, 0.f};
    f32x4 acc[4];
#pragma unroll
    for (int ct = 0; ct < 4; ++ct) acc[ct] = z;

    const unsigned short* ap = xb + (row0 + lr) * 512 + lg * 8;
#pragma unroll 4
    for (int k0 = 0; k0 < 512; k0 += 32) {
        bf16x8 a = *(const bf16x8*)(ap + k0);
#pragma unroll
        for (int ct = 0; ct < 4; ++ct) {
            bf16x8 b = *(const bf16x8*)(wt + (col0 + ct * 16 + lr) * 512 + k0 + lg * 8);
            acc[ct] = mfma16(a, b, acc[ct]);
        }
    }

#pragma unroll
    for (int ct = 0; ct < 4; ++ct) {
#pragma unroll
        for (int i = 0; i < 4; ++i) {
            int gr = row0 + lg * 4 + i;          // 0..4095
            int gc = col0 + ct * 16 + lr;        // 0..1663
            float v = acc[ct][i];
            int b = gr >> 11, in = gr & 2047;
            if (gc < 512) {
                int s = gc >> 6, d = gc & 63;
                qs[((b * 8 + s) * 2048 + in) * 64 + d] = f2b(v * SCALE_L2E);
            } else if (gc < 1024) {
                int c = gc - 512; int s = c >> 6, d = c & 63;
                ks[((b * 8 + s) * 2048 + in) * 64 + d] = f2b(v);
            } else if (gc < 1152) {
                int c = gc - 1024;               // 0..127 = r*64+d
                vt[(b * 128 + c) * 2048 + in] = f2b(v);
            } else {
                int c = gc - 1152; int s = c >> 6, d = c & 63;
                rqb[((b * 8 + s) * 2048 + in) * 64 + d] = f2b(v * SCALE_L2E);
            }
        }
    }
}

// ---------------------------------------------------------------------------
// K2: flash attention (stage 1) + fused retrieval composition (stage 2).
// In-block split-KV: grid 1024 = (b*s)[16] x qtile32[64]; 4 waves:
//   wave w: q-rows (w&1)*16..+16, kv-half h=w>>1.
// Register discipline (R4 lesson): NO multi-tile prefetch arrays — K and V
// fragments are transient (loaded just before use); latency is hidden by
// TLP (4 waves/SIMD), not ILP. Live VGPR ~110 < 128 cap -> no spill.
// ---------------------------------------------------------------------------
__global__ __launch_bounds__(256, 4) void k_attn(const unsigned short* __restrict__ qs,
                                                 const unsigned short* __restrict__ ks,
                                                 const unsigned short* __restrict__ rqb,
                                                 const unsigned short* __restrict__ vt,
                                                 const unsigned short* __restrict__ wkt,
                                                 unsigned short* __restrict__ ob)
{
    __shared__ unsigned short p_lds[4][16][72];       // 9.2 KB (pad 64->72)
    __shared__ float mrg[2][16][132];                 // 16.9 KB (pad 128->132)
    __shared__ float ml[2][16][2];                    // 256 B

    const int tid = threadIdx.x;
    const int lane = tid & 63, wid = tid >> 6;
    const int lr = lane & 15, lg = lane >> 4;
    const int bid = blockIdx.x;
    const int bs = bid >> 6, qt = bid & 63;           // bs = b*8+s
    const int gb = bs >> 3, gs = bs & 7;
    const int qrow0 = qt * 32 + (wid & 1) * 16;
    const int h = wid >> 1;                           // kv half

    // Q fragments, kept in registers for the whole main loop
    const unsigned short* qbase = qs + ((size_t)bs * 2048 + qrow0 + lr) * 64 + lg * 8;
    const bf16x8 q0 = *(const bf16x8*)(qbase);
    const bf16x8 q1 = *(const bf16x8*)(qbase + 32);

    const unsigned short* kpl = ks + (size_t)bs * 131072 + h * 65536 + lr * 64 + lg * 8;
    const unsigned short* vpl = vt + (size_t)gb * 262144 + lr * 2048 + h * 1024 + lg * 8;

    const f32x4 z = {0.f, 0.f, 0.f, 0.f};
    bf16x8 ones;
#pragma unroll
    for (int j = 0; j < 8; ++j) ones[j] = (short)0x3F80;

    float m_r[4];
    f32x4 acc[8];
    f32x4 acc_l = z;
#pragma unroll
    for (int i = 0; i < 4; ++i) m_r[i] = -3.0e38f;
#pragma unroll
    for (int c8 = 0; c8 < 8; ++c8) acc[c8] = z;

    for (int kt = 0; kt < 16; ++kt) {
        const int k0 = kt * 64;

        // --- S = Q K^T (16 x 64 tile), K frags transient (8 regs per ct)
        f32x4 s[4];
#pragma unroll
        for (int ct = 0; ct < 4; ++ct) {
            const unsigned short* kp = kpl + k0 * 64 + ct * 1024;
            bf16x8 kf0 = *(const bf16x8*)(kp);
            bf16x8 kf1 = *(const bf16x8*)(kp + 32);
            f32x4 t = z;
            t = mfma16(q0, kf0, t);
            t = mfma16(q1, kf1, t);
            s[ct] = t;
        }

        // --- deferred-max online softmax (all values in log2 units)
        float lm[4];
        bool need = false;
#pragma unroll
        for (int i = 0; i < 4; ++i) {
            lm[i] = fmaxf(fmaxf(s[0][i], s[1][i]), fmaxf(s[2][i], s[3][i]));
            need = need || (lm[i] > m_r[i] + 8.0f);
        }
        if (__any(need)) {
#pragma unroll
            for (int i = 0; i < 4; ++i) {
                float mx = lm[i];
                mx = fmaxf(mx, __shfl_xor(mx, 1, 16));
                mx = fmaxf(mx, __shfl_xor(mx, 2, 16));
                mx = fmaxf(mx, __shfl_xor(mx, 4, 16));
                mx = fmaxf(mx, __shfl_xor(mx, 8, 16));
                float m_new = fmaxf(m_r[i], mx);
                float alpha = exp2f(m_r[i] - m_new);
#pragma unroll
                for (int c8 = 0; c8 < 8; ++c8) acc[c8][i] *= alpha;
                acc_l[i] *= alpha;
                m_r[i] = m_new;
            }
        }
        // --- P = exp2(S - m), bf16, through wave-private LDS tile
#pragma unroll
        for (int i = 0; i < 4; ++i) {
#pragma unroll
            for (int ct = 0; ct < 4; ++ct)
                p_lds[wid][lg * 4 + i][ct * 16 + lr] = f2b_hw(exp2f(s[ct][i] - m_r[i]));
        }
        bf16x8 pf0 = *(const bf16x8*)(&p_lds[wid][lr][lg * 8]);
        bf16x8 pf1 = *(const bf16x8*)(&p_lds[wid][lr][32 + lg * 8]);

        // --- PV: V frags transient per c8 (+ row-sum via ones-column)
#pragma unroll
        for (int c8 = 0; c8 < 8; ++c8) {
            const unsigned short* vp = vpl + c8 * 32768 + k0;
            bf16x8 vf0 = *(const bf16x8*)(vp);
            bf16x8 vf1 = *(const bf16x8*)(vp + 32);
            acc[c8] = mfma16(pf0, vf0, acc[c8]);
            acc[c8] = mfma16(pf1, vf1, acc[c8]);
        }
        acc_l = mfma16(pf0, ones, acc_l);
        acc_l = mfma16(pf1, ones, acc_l);
    }

    // --- split-KV merge through LDS: h=1 waves publish fp32 partials
    if (h == 1) {
#pragma unroll
        for (int c8 = 0; c8 < 8; ++c8)
#pragma unroll
            for (int i = 0; i < 4; ++i)
                mrg[wid & 1][lg * 4 + i][c8 * 16 + lr] = acc[c8][i];
        if (lr == 0) {
#pragma unroll
            for (int i = 0; i < 4; ++i) {
                ml[wid & 1][lg * 4 + i][0] = m_r[i];
                ml[wid & 1][lg * 4 + i][1] = acc_l[i];
            }
        }
    }
    __syncthreads();
    if (h == 1) return;

    const int slot = wid & 1;

    // rq fragments (pre-scaled by DH^-0.5*log2e in k_proj)
    const unsigned short* rqbase = rqb + ((size_t)bs * 2048 + qrow0 + lr) * 64 + lg * 8;
    const bf16x8 rq0 = *(const bf16x8*)(rqbase);
    const bf16x8 rq1 = *(const bf16x8*)(rqbase + 32);

    // merge partner partials
    float inv[4];
    f32x4 accM[8];
#pragma unroll
    for (int i = 0; i < 4; ++i) {
        float m_b = ml[slot][lg * 4 + i][0];
        float l_b = ml[slot][lg * 4 + i][1];
        float m_new = fmaxf(m_r[i], m_b);
        float fa = exp2f(m_r[i] - m_new);
        float fb = exp2f(m_b - m_new);
        inv[i] = 1.0f / (acc_l[i] * fa + l_b * fb);
#pragma unroll
        for (int c8 = 0; c8 < 8; ++c8)
            accM[c8][i] = acc[c8][i] * fa + mrg[slot][lg * 4 + i][c8 * 16 + lr] * fb;
    }

    // --- stage 2 via MFMA: T[q][d] = sum_dp rq[q][dp] * wk_ret[d][dp]
    f32x4 Tt[4];
#pragma unroll
    for (int ct = 0; ct < 4; ++ct) {
        bf16x8 wb0 = *(const bf16x8*)(wkt + (ct * 16 + lr) * 64 + lg * 8);
        bf16x8 wb1 = *(const bf16x8*)(wkt + (ct * 16 + lr) * 64 + 32 + lg * 8);
        f32x4 t = z;
        t = mfma16(rq0, wb0, t);
        t = mfma16(rq1, wb1, t);
        Tt[ct] = t;
    }

    // sim_r[row] = sum_{d} T[row][d] * retrN[row][r*64+d]   (log2 units)
    float w0v[4], w1v[4];
#pragma unroll
    for (int i = 0; i < 4; ++i) {
        float s0 = 0.f, s1 = 0.f;
#pragma unroll
        for (int ct = 0; ct < 4; ++ct) {
            s0 += Tt[ct][i] * accM[ct][i];
            s1 += Tt[ct][i] * accM[4 + ct][i];
        }
        s0 *= inv[i]; s1 *= inv[i];
        s0 += __shfl_xor(s0, 1, 16); s1 += __shfl_xor(s1, 1, 16);
        s0 += __shfl_xor(s0, 2, 16); s1 += __shfl_xor(s1, 2, 16);
        s0 += __shfl_xor(s0, 4, 16); s1 += __shfl_xor(s1, 4, 16);
        s0 += __shfl_xor(s0, 8, 16); s1 += __shfl_xor(s1, 8, 16);
        float mm = fmaxf(s0, s1);
        float e0 = exp2f(s0 - mm), e1 = exp2f(s1 - mm);
        float inw = 1.0f / (e0 + e1);
        w0v[i] = e0 * inw; w1v[i] = e1 * inw;
    }

    // --- combine r=2 and store ob[b][n][gs*64 + d]
#pragma unroll
    for (int ct = 0; ct < 4; ++ct) {
#pragma unroll
        for (int i = 0; i < 4; ++i) {
            float o = (w0v[i] * accM[ct][i] + w1v[i] * accM[4 + ct][i]) * inv[i];
            ob[((size_t)gb * 2048 + qrow0 + lg * 4 + i) * 512 + gs * 64 + ct * 16 + lr] = f2b_hw(o);
        }
    }
}

// ---------------------------------------------------------------------------
// K3: final GEMM  out[4096][512] (fp32) = ob(bf16) @ w_out, via wot = w_out^T
// grid (64, 8), 256 threads
// ---------------------------------------------------------------------------
__global__ __launch_bounds__(256) void k_out(const unsigned short* __restrict__ ob,
                                             const unsigned short* __restrict__ wot,
                                             float* __restrict__ out)
{
    const int lane = threadIdx.x & 63, wid = threadIdx.x >> 6;
    const int lr = lane & 15, lg = lane >> 4;
    const int row0 = blockIdx.x * 64 + wid * 16;
    const int col0 = blockIdx.y * 64;

    const f32x4 z = {0.f, 0.f, 0.f, 0.f};
    f32x4 acc[4];
#pragma unroll
    for (int ct = 0; ct < 4; ++ct) acc[ct] = z;

    const unsigned short* ap = ob + (row0 + lr) * 512 + lg * 8;
#pragma unroll 4
    for (int k0 = 0; k0 < 512; k0 += 32) {
        bf16x8 a = *(const bf16x8*)(ap + k0);
#pragma unroll
        for (int ct = 0; ct < 4; ++ct) {
            bf16x8 b = *(const bf16x8*)(wot + (col0 + ct * 16 + lr) * 512 + k0 + lg * 8);
            acc[ct] = mfma16(a, b, acc[ct]);
        }
    }
#pragma unroll
    for (int ct = 0; ct < 4; ++ct)
#pragma unroll
        for (int i = 0; i < 4; ++i)
            out[(size_t)(row0 + lg * 4 + i) * 512 + col0 + ct * 16 + lr] = acc[ct][i];
}

// ---------------------------------------------------------------------------
extern "C" void kernel_launch(void* const* d_in, const int* in_sizes, int n_in,
                              void* d_out, int out_size, void* d_ws, size_t ws_size,
                              hipStream_t stream)
{
    (void)in_sizes; (void)n_in; (void)out_size; (void)ws_size;
    const float* x      = (const float*)d_in[0];
    const float* wq_s   = (const float*)d_in[1];
    const float* wk_s   = (const float*)d_in[2];
    const float* wv_r   = (const float*)d_in[3];
    const float* wq_r   = (const float*)d_in[4];
    const float* wk_ret = (const float*)d_in[5];
    const float* w_out  = (const float*)d_in[6];

    char* ws = (char*)d_ws;                            // needs ~24.3 MB
    unsigned short* xb  = (unsigned short*)(ws + 0);          // [4096][512]
    unsigned short* wt  = (unsigned short*)(ws + 4194304);    // [1664][512]
    unsigned short* qsb = (unsigned short*)(ws + 5898240);    // [2][8][2048][64]
    unsigned short* ksb = (unsigned short*)(ws + 10092544);   // [2][8][2048][64]
    unsigned short* rqb = (unsigned short*)(ws + 14286848);   // [2][8][2048][64]
    unsigned short* vtb = (unsigned short*)(ws + 18481152);   // [2][128][2048]
    unsigned short* obb = (unsigned short*)(ws + 19529728);   // [2][2048][512]
    unsigned short* wot = (unsigned short*)(ws + 23724032);   // [512][512]
    unsigned short* wkt = (unsigned short*)(ws + 24248320);   // [64][64]

    hipLaunchKernelGGL(k_convert, dim3(2048), dim3(256), 0, stream,
                       x, wq_s, wk_s, wv_r, wq_r, wk_ret, w_out, xb, wt, wot, wkt);
    hipLaunchKernelGGL(k_proj, dim3(64, 26), dim3(256), 0, stream,
                       xb, wt, qsb, ksb, rqb, vtb);
    hipLaunchKernelGGL(k_attn, dim3(1024), dim3(256), 0, stream,
                       qsb, ksb, rqb, vtb, wkt, obb);
    hipLaunchKernelGGL(k_out, dim3(64, 8), dim3(256), 0, stream,
                       obb, wot, (float*)d_out);
}

// Round 6
// 274.295 us; speedup vs baseline: 1.5564x; 1.0006x over previous
//
#include <hip/hip_runtime.h>
#include <hip/hip_bf16.h>

#define DEV __device__ __forceinline__

typedef __attribute__((ext_vector_type(8))) short bf16x8;
typedef __attribute__((ext_vector_type(4))) float f32x4;

DEV float b2f(unsigned short u) {
    unsigned int v = ((unsigned int)u) << 16;
    float f; __builtin_memcpy(&f, &v, 4); return f;
}
DEV unsigned short f2b(float f) {            // RNE via bit-ops
    unsigned int v; __builtin_memcpy(&v, &f, 4);
    v = (v + 0x7fffu + ((v >> 16) & 1u)) >> 16;
    return (unsigned short)v;
}
DEV unsigned short f2b_hw(float f) {         // hardware cvt (RNE)
    __hip_bfloat16 h = __float2bfloat16(f);
    unsigned short u; __builtin_memcpy(&u, &h, 2); return u;
}

DEV f32x4 mfma16(bf16x8 a, bf16x8 b, f32x4 c) {
    return __builtin_amdgcn_mfma_f32_16x16x32_bf16(a, b, c, 0, 0, 0);
}

constexpr float SCALE_L2E = 0.125f * 1.44269504088896340736f;  // DH^-0.5 * log2(e)

// ---------------------------------------------------------------------------
// K0: fp32 -> bf16 conversions.
//  xb[4096][512]  = x
//  wt[1664][512]  = [wq_s | wk_s | wv_r | wq_r]^T  (B^T form for MFMA)
//  wot[512][512]  = w_out^T
//  wkt[64][64]    = wk_ret ROW-MAJOR (B^T form for T = RQ @ wk_ret^T)
// ---------------------------------------------------------------------------
__global__ void k_convert(const float* __restrict__ x,
                          const float* __restrict__ wq_s, const float* __restrict__ wk_s,
                          const float* __restrict__ wv_r, const float* __restrict__ wq_r,
                          const float* __restrict__ wk_ret, const float* __restrict__ w_out,
                          unsigned short* __restrict__ xb,
                          unsigned short* __restrict__ wt,
                          unsigned short* __restrict__ wot,
                          unsigned short* __restrict__ wkt)
{
    const int T1 = 4096 * 512;
    const int T2 = 1664 * 512;
    const int T3 = 512 * 512;
    const int T4 = 64 * 64;
    const int total = T1 + T2 + T3 + T4;
    for (int idx = blockIdx.x * blockDim.x + threadIdx.x; idx < total;
         idx += gridDim.x * blockDim.x) {
        if (idx < T1) {
            xb[idx] = f2b(x[idx]);
        } else if (idx < T1 + T2) {
            int t = idx - T1;
            int n = t >> 9, k = t & 511;   // t == n*512 + k
            float v;
            if (n < 512)       v = wq_s[k * 512 + n];
            else if (n < 1024) v = wk_s[k * 512 + (n - 512)];
            else if (n < 1152) v = wv_r[k * 128 + (n - 1024)];
            else               v = wq_r[k * 512 + (n - 1152)];
            wt[t] = f2b(v);
        } else if (idx < T1 + T2 + T3) {
            int t = idx - T1 - T2;
            int n = t >> 9, k = t & 511;
            wot[t] = f2b(w_out[k * 512 + n]);
        } else {
            int t = idx - T1 - T2 - T3;
            wkt[t] = f2b(wk_ret[t]);       // identity copy (row-major B^T)
        }
    }
}

// ---------------------------------------------------------------------------
// K1: projection GEMM  C[4096][1664] = xb @ wt^T, epilogue scatters into
//     qs/ks/rqb  (bf16[b][s][n][64], q's pre-scaled by DH^-0.5 * log2e)
//     and vt (bf16[b][128][n], transposed V).
// grid (64, 26), 256 threads (4 waves x 16 rows, 64 cols/block)
// ---------------------------------------------------------------------------
__global__ __launch_bounds__(256) void k_proj(const unsigned short* __restrict__ xb,
                                              const unsigned short* __restrict__ wt,
                                              unsigned short* __restrict__ qs,
                                              unsigned short* __restrict__ ks,
                                              unsigned short* __restrict__ rqb,
                                              unsigned short* __restrict__ vt)
{
    const int lane = threadIdx.x & 63, wid = threadIdx.x >> 6;
    const int lr = lane & 15, lg = lane >> 4;
    const int row0 = blockIdx.x * 64 + wid * 16;
    const int col0 = blockIdx.y * 64;

    const f32x4 z = {0.f, 0.f, 0.f, 0.f};
    f32x4 acc[4];
#pragma unroll
    for (int ct = 0; ct < 4; ++ct) acc[ct] = z;

    const unsigned short* ap = xb + (row0 + lr) * 512 + lg * 8;
#pragma unroll 4
    for (int k0 = 0; k0 < 512; k0 += 32) {
        bf16x8 a = *(const bf16x8*)(ap + k0);
#pragma unroll
        for (int ct = 0; ct < 4; ++ct) {
            bf16x8 b = *(const bf16x8*)(wt + (col0 + ct * 16 + lr) * 512 + k0 + lg * 8);
            acc[ct] = mfma16(a, b, acc[ct]);
        }
    }

#pragma unroll
    for (int ct = 0; ct < 4; ++ct) {
#pragma unroll
        for (int i = 0; i < 4; ++i) {
            int gr = row0 + lg * 4 + i;          // 0..4095
            int gc = col0 + ct * 16 + lr;        // 0..1663
            float v = acc[ct][i];
            int b = gr >> 11, in = gr & 2047;
            if (gc < 512) {
                int s = gc >> 6, d = gc & 63;
                qs[((b * 8 + s) * 2048 + in) * 64 + d] = f2b(v * SCALE_L2E);
            } else if (gc < 1024) {
                int c = gc - 512; int s = c >> 6, d = c & 63;
                ks[((b * 8 + s) * 2048 + in) * 64 + d] = f2b(v);
            } else if (gc < 1152) {
                int c = gc - 1024;               // 0..127 = r*64+d
                vt[(b * 128 + c) * 2048 + in] = f2b(v);
            } else {
                int c = gc - 1152; int s = c >> 6, d = c & 63;
                rqb[((b * 8 + s) * 2048 + in) * 64 + d] = f2b(v * SCALE_L2E);
            }
        }
    }
}

// ---------------------------------------------------------------------------
// K2: flash attention (stage 1) + fused retrieval composition (stage 2).
// In-block split-KV: grid 1024 = (b*s)[16] x qtile32[64]; 4 waves:
//   wave w: q-rows (w&1)*16..+16, kv-half h=w>>1.
// R6: explicit load batching pinned with sched_barrier(0) — V-frags for the
// current tile issued at tile top, K-frags for the NEXT tile issued right
// after QK^T; __launch_bounds__(256,2) gives the ~230-reg budget this needs
// (R4 proved 128 spills; R5 proved 128-no-spill goes JIT-serial on loads).
// ---------------------------------------------------------------------------
__global__ __launch_bounds__(256, 2) void k_attn(const unsigned short* __restrict__ qs,
                                                 const unsigned short* __restrict__ ks,
                                                 const unsigned short* __restrict__ rqb,
                                                 const unsigned short* __restrict__ vt,
                                                 const unsigned short* __restrict__ wkt,
                                                 unsigned short* __restrict__ ob)
{
    __shared__ unsigned short p_lds[4][16][72];       // 9.2 KB (pad 64->72)
    __shared__ float mrg[2][16][132];                 // 16.9 KB (pad 128->132)
    __shared__ float ml[2][16][2];                    // 256 B

    const int tid = threadIdx.x;
    const int lane = tid & 63, wid = tid >> 6;
    const int lr = lane & 15, lg = lane >> 4;
    const int bid = blockIdx.x;
    const int bs = bid >> 6, qt = bid & 63;           // bs = b*8+s
    const int gb = bs >> 3, gs = bs & 7;
    const int qrow0 = qt * 32 + (wid & 1) * 16;
    const int h = wid >> 1;                           // kv half

    // Q fragments, kept in registers for the whole main loop
    const unsigned short* qbase = qs + ((size_t)bs * 2048 + qrow0 + lr) * 64 + lg * 8;
    const bf16x8 q0 = *(const bf16x8*)(qbase);
    const bf16x8 q1 = *(const bf16x8*)(qbase + 32);

    const unsigned short* kpl = ks + (size_t)bs * 131072 + h * 65536 + lr * 64 + lg * 8;
    const unsigned short* vpl = vt + (size_t)gb * 262144 + lr * 2048 + h * 1024 + lg * 8;

    const f32x4 z = {0.f, 0.f, 0.f, 0.f};
    bf16x8 ones;
#pragma unroll
    for (int j = 0; j < 8; ++j) ones[j] = (short)0x3F80;

    float m_r[4];
    f32x4 acc[8];
    f32x4 acc_l = z;
#pragma unroll
    for (int i = 0; i < 4; ++i) m_r[i] = -3.0e38f;
#pragma unroll
    for (int c8 = 0; c8 < 8; ++c8) acc[c8] = z;

    // preload K frags for tile 0 (8 x 16B)
    bf16x8 kf[8];
#pragma unroll
    for (int ct = 0; ct < 4; ++ct)
#pragma unroll
        for (int ksb = 0; ksb < 2; ++ksb)
            kf[ct * 2 + ksb] = *(const bf16x8*)(kpl + ct * 1024 + ksb * 32);
    __builtin_amdgcn_sched_barrier(0);

    for (int kt = 0; kt < 16; ++kt) {
        const int k0 = kt * 64;

        // --- (1) issue ALL V loads for this tile; pinned here by (2)
        bf16x8 vf[16];
#pragma unroll
        for (int c8 = 0; c8 < 8; ++c8)
#pragma unroll
            for (int ksb = 0; ksb < 2; ++ksb)
                vf[c8 * 2 + ksb] = *(const bf16x8*)(vpl + c8 * 32768 + k0 + ksb * 32);
        // --- (2) pin: V loads must issue before anything below
        __builtin_amdgcn_sched_barrier(0);

        // --- (3) S = Q K^T (16 x 64 tile) with current K frags
        f32x4 s[4];
#pragma unroll
        for (int ct = 0; ct < 4; ++ct) {
            f32x4 t = z;
            t = mfma16(q0, kf[ct * 2 + 0], t);
            t = mfma16(q1, kf[ct * 2 + 1], t);
            s[ct] = t;
        }

        // --- (4) issue next-tile K loads; pinned before softmax/PV
        bf16x8 kn[8];
        if (kt != 15) {
#pragma unroll
            for (int ct = 0; ct < 4; ++ct)
#pragma unroll
                for (int ksb = 0; ksb < 2; ++ksb)
                    kn[ct * 2 + ksb] = *(const bf16x8*)(kpl + (k0 + 64) * 64 + ct * 1024 + ksb * 32);
        }
        __builtin_amdgcn_sched_barrier(0);

        // --- (5) deferred-max online softmax (log2 units)
        float lm[4];
        bool need = false;
#pragma unroll
        for (int i = 0; i < 4; ++i) {
            lm[i] = fmaxf(fmaxf(s[0][i], s[1][i]), fmaxf(s[2][i], s[3][i]));
            need = need || (lm[i] > m_r[i] + 8.0f);
        }
        if (__any(need)) {
#pragma unroll
            for (int i = 0; i < 4; ++i) {
                float mx = lm[i];
                mx = fmaxf(mx, __shfl_xor(mx, 1, 16));
                mx = fmaxf(mx, __shfl_xor(mx, 2, 16));
                mx = fmaxf(mx, __shfl_xor(mx, 4, 16));
                mx = fmaxf(mx, __shfl_xor(mx, 8, 16));
                float m_new = fmaxf(m_r[i], mx);
                float alpha = exp2f(m_r[i] - m_new);
#pragma unroll
                for (int c8 = 0; c8 < 8; ++c8) acc[c8][i] *= alpha;
                acc_l[i] *= alpha;
                m_r[i] = m_new;
            }
        }
        // --- (6) P = exp2(S - m), bf16, through wave-private LDS tile
#pragma unroll
        for (int i = 0; i < 4; ++i) {
#pragma unroll
            for (int ct = 0; ct < 4; ++ct)
                p_lds[wid][lg * 4 + i][ct * 16 + lr] = f2b_hw(exp2f(s[ct][i] - m_r[i]));
        }
        bf16x8 pf0 = *(const bf16x8*)(&p_lds[wid][lr][lg * 8]);
        bf16x8 pf1 = *(const bf16x8*)(&p_lds[wid][lr][32 + lg * 8]);

        // --- (7) PV with batched V frags (+ row-sum via ones-column)
#pragma unroll
        for (int c8 = 0; c8 < 8; ++c8) {
            acc[c8] = mfma16(pf0, vf[c8 * 2 + 0], acc[c8]);
            acc[c8] = mfma16(pf1, vf[c8 * 2 + 1], acc[c8]);
        }
        acc_l = mfma16(pf0, ones, acc_l);
        acc_l = mfma16(pf1, ones, acc_l);

        // --- (8) rotate K buffer
        if (kt != 15) {
#pragma unroll
            for (int j = 0; j < 8; ++j) kf[j] = kn[j];
        }
    }

    // --- split-KV merge through LDS: h=1 waves publish fp32 partials
    if (h == 1) {
#pragma unroll
        for (int c8 = 0; c8 < 8; ++c8)
#pragma unroll
            for (int i = 0; i < 4; ++i)
                mrg[wid & 1][lg * 4 + i][c8 * 16 + lr] = acc[c8][i];
        if (lr == 0) {
#pragma unroll
            for (int i = 0; i < 4; ++i) {
                ml[wid & 1][lg * 4 + i][0] = m_r[i];
                ml[wid & 1][lg * 4 + i][1] = acc_l[i];
            }
        }
    }
    __syncthreads();
    if (h == 1) return;

    const int slot = wid & 1;

    // rq fragments (pre-scaled by DH^-0.5*log2e in k_proj)
    const unsigned short* rqbase = rqb + ((size_t)bs * 2048 + qrow0 + lr) * 64 + lg * 8;
    const bf16x8 rq0 = *(const bf16x8*)(rqbase);
    const bf16x8 rq1 = *(const bf16x8*)(rqbase + 32);

    // merge partner partials
    float inv[4];
    f32x4 accM[8];
#pragma unroll
    for (int i = 0; i < 4; ++i) {
        float m_b = ml[slot][lg * 4 + i][0];
        float l_b = ml[slot][lg * 4 + i][1];
        float m_new = fmaxf(m_r[i], m_b);
        float fa = exp2f(m_r[i] - m_new);
        float fb = exp2f(m_b - m_new);
        inv[i] = 1.0f / (acc_l[i] * fa + l_b * fb);
#pragma unroll
        for (int c8 = 0; c8 < 8; ++c8)
            accM[c8][i] = acc[c8][i] * fa + mrg[slot][lg * 4 + i][c8 * 16 + lr] * fb;
    }

    // --- stage 2 via MFMA: T[q][d] = sum_dp rq[q][dp] * wk_ret[d][dp]
    f32x4 Tt[4];
#pragma unroll
    for (int ct = 0; ct < 4; ++ct) {
        bf16x8 wb0 = *(const bf16x8*)(wkt + (ct * 16 + lr) * 64 + lg * 8);
        bf16x8 wb1 = *(const bf16x8*)(wkt + (ct * 16 + lr) * 64 + 32 + lg * 8);
        f32x4 t = z;
        t = mfma16(rq0, wb0, t);
        t = mfma16(rq1, wb1, t);
        Tt[ct] = t;
    }

    // sim_r[row] = sum_{d} T[row][d] * retrN[row][r*64+d]   (log2 units)
    float w0v[4], w1v[4];
#pragma unroll
    for (int i = 0; i < 4; ++i) {
        float s0 = 0.f, s1 = 0.f;
#pragma unroll
        for (int ct = 0; ct < 4; ++ct) {
            s0 += Tt[ct][i] * accM[ct][i];
            s1 += Tt[ct][i] * accM[4 + ct][i];
        }
        s0 *= inv[i]; s1 *= inv[i];
        s0 += __shfl_xor(s0, 1, 16); s1 += __shfl_xor(s1, 1, 16);
        s0 += __shfl_xor(s0, 2, 16); s1 += __shfl_xor(s1, 2, 16);
        s0 += __shfl_xor(s0, 4, 16); s1 += __shfl_xor(s1, 4, 16);
        s0 += __shfl_xor(s0, 8, 16); s1 += __shfl_xor(s1, 8, 16);
        float mm = fmaxf(s0, s1);
        float e0 = exp2f(s0 - mm), e1 = exp2f(s1 - mm);
        float inw = 1.0f / (e0 + e1);
        w0v[i] = e0 * inw; w1v[i] = e1 * inw;
    }

    // --- combine r=2 and store ob[b][n][gs*64 + d]
#pragma unroll
    for (int ct = 0; ct < 4; ++ct) {
#pragma unroll
        for (int i = 0; i < 4; ++i) {
            float o = (w0v[i] * accM[ct][i] + w1v[i] * accM[4 + ct][i]) * inv[i];
            ob[((size_t)gb * 2048 + qrow0 + lg * 4 + i) * 512 + gs * 64 + ct * 16 + lr] = f2b_hw(o);
        }
    }
}

// ---------------------------------------------------------------------------
// K3: final GEMM  out[4096][512] (fp32) = ob(bf16) @ w_out, via wot = w_out^T
// grid (64, 8), 256 threads
// ---------------------------------------------------------------------------
__global__ __launch_bounds__(256) void k_out(const unsigned short* __restrict__ ob,
                                             const unsigned short* __restrict__ wot,
                                             float* __restrict__ out)
{
    const int lane = threadIdx.x & 63, wid = threadIdx.x >> 6;
    const int lr = lane & 15, lg = lane >> 4;
    const int row0 = blockIdx.x * 64 + wid * 16;
    const int col0 = blockIdx.y * 64;

    const f32x4 z = {0.f, 0.f, 0.f, 0.f};
    f32x4 acc[4];
#pragma unroll
    for (int ct = 0; ct < 4; ++ct) acc[ct] = z;

    const unsigned short* ap = ob + (row0 + lr) * 512 + lg * 8;
#pragma unroll 4
    for (int k0 = 0; k0 < 512; k0 += 32) {
        bf16x8 a = *(const bf16x8*)(ap + k0);
#pragma unroll
        for (int ct = 0; ct < 4; ++ct) {
            bf16x8 b = *(const bf16x8*)(wot + (col0 + ct * 16 + lr) * 512 + k0 + lg * 8);
            acc[ct] = mfma16(a, b, acc[ct]);
        }
    }
#pragma unroll
    for (int ct = 0; ct < 4; ++ct)
#pragma unroll
        for (int i = 0; i < 4; ++i)
            out[(size_t)(row0 + lg * 4 + i) * 512 + col0 + ct * 16 + lr] = acc[ct][i];
}

// ---------------------------------------------------------------------------
extern "C" void kernel_launch(void* const* d_in, const int* in_sizes, int n_in,
                              void* d_out, int out_size, void* d_ws, size_t ws_size,
                              hipStream_t stream)
{
    (void)in_sizes; (void)n_in; (void)out_size; (void)ws_size;
    const float* x      = (const float*)d_in[0];
    const float* wq_s   = (const float*)d_in[1];
    const float* wk_s   = (const float*)d_in[2];
    const float* wv_r   = (const float*)d_in[3];
    const float* wq_r   = (const float*)d_in[4];
    const float* wk_ret = (const float*)d_in[5];
    const float* w_out  = (const float*)d_in[6];

    char* ws = (char*)d_ws;                            // needs ~24.3 MB
    unsigned short* xb  = (unsigned short*)(ws + 0);          // [4096][512]
    unsigned short* wt  = (unsigned short*)(ws + 4194304);    // [1664][512]
    unsigned short* qsb = (unsigned short*)(ws + 5898240);    // [2][8][2048][64]
    unsigned short* ksb = (unsigned short*)(ws + 10092544);   // [2][8][2048][64]
    unsigned short* rqb = (unsigned short*)(ws + 14286848);   // [2][8][2048][64]
    unsigned short* vtb = (unsigned short*)(ws + 18481152);   // [2][128][2048]
    unsigned short* obb = (unsigned short*)(ws + 19529728);   // [2][2048][512]
    unsigned short* wot = (unsigned short*)(ws + 23724032);   // [512][512]
    unsigned short* wkt = (unsigned short*)(ws + 24248320);   // [64][64]

    hipLaunchKernelGGL(k_convert, dim3(2048), dim3(256), 0, stream,
                       x, wq_s, wk_s, wv_r, wq_r, wk_ret, w_out, xb, wt, wot, wkt);
    hipLaunchKernelGGL(k_proj, dim3(64, 26), dim3(256), 0, stream,
                       xb, wt, qsb, ksb, rqb, vtb);
    hipLaunchKernelGGL(k_attn, dim3(1024), dim3(256), 0, stream,
                       qsb, ksb, rqb, vtb, wkt, obb);
    hipLaunchKernelGGL(k_out, dim3(64, 8), dim3(256), 0, stream,
                       obb, wot, (float*)d_out);
}

// Round 7
// 155.946 us; speedup vs baseline: 2.7375x; 1.7589x over previous
//
#include <hip/hip_runtime.h>
#include <hip/hip_bf16.h>

#define DEV __device__ __forceinline__

typedef __attribute__((ext_vector_type(8))) short bf16x8;
typedef __attribute__((ext_vector_type(4))) float f32x4;

DEV float b2f(unsigned short u) {
    unsigned int v = ((unsigned int)u) << 16;
    float f; __builtin_memcpy(&f, &v, 4); return f;
}
DEV unsigned short f2b(float f) {            // RNE via bit-ops
    unsigned int v; __builtin_memcpy(&v, &f, 4);
    v = (v + 0x7fffu + ((v >> 16) & 1u)) >> 16;
    return (unsigned short)v;
}
DEV unsigned short f2b_hw(float f) {         // hardware cvt (RNE)
    __hip_bfloat16 h = __float2bfloat16(f);
    unsigned short u; __builtin_memcpy(&u, &h, 2); return u;
}

DEV f32x4 mfma16(bf16x8 a, bf16x8 b, f32x4 c) {
    return __builtin_amdgcn_mfma_f32_16x16x32_bf16(a, b, c, 0, 0, 0);
}

// global -> LDS async copy, 16B per lane; lds dest = uniform base + lane*16
DEV void stage16(const void* g, void* l) {
    __builtin_amdgcn_global_load_lds((const __attribute__((address_space(1))) void*)g,
                                     (__attribute__((address_space(3))) void*)l, 16, 0, 0);
}

constexpr float SCALE_L2E = 0.125f * 1.44269504088896340736f;  // DH^-0.5 * log2(e)

// ---------------------------------------------------------------------------
// K0: fp32 -> bf16 conversions.
//  xb[4096][512]  = x
//  wt[1664][512]  = [wq_s | wk_s | wv_r | wq_r]^T  (B^T form for MFMA)
//  wot[512][512]  = w_out^T
//  wkt[64][64]    = wk_ret ROW-MAJOR (B^T form for T = RQ @ wk_ret^T)
// ---------------------------------------------------------------------------
__global__ void k_convert(const float* __restrict__ x,
                          const float* __restrict__ wq_s, const float* __restrict__ wk_s,
                          const float* __restrict__ wv_r, const float* __restrict__ wq_r,
                          const float* __restrict__ wk_ret, const float* __restrict__ w_out,
                          unsigned short* __restrict__ xb,
                          unsigned short* __restrict__ wt,
                          unsigned short* __restrict__ wot,
                          unsigned short* __restrict__ wkt)
{
    const int T1 = 4096 * 512;
    const int T2 = 1664 * 512;
    const int T3 = 512 * 512;
    const int T4 = 64 * 64;
    const int total = T1 + T2 + T3 + T4;
    for (int idx = blockIdx.x * blockDim.x + threadIdx.x; idx < total;
         idx += gridDim.x * blockDim.x) {
        if (idx < T1) {
            xb[idx] = f2b(x[idx]);
        } else if (idx < T1 + T2) {
            int t = idx - T1;
            int n = t >> 9, k = t & 511;   // t == n*512 + k
            float v;
            if (n < 512)       v = wq_s[k * 512 + n];
            else if (n < 1024) v = wk_s[k * 512 + (n - 512)];
            else if (n < 1152) v = wv_r[k * 128 + (n - 1024)];
            else               v = wq_r[k * 512 + (n - 1152)];
            wt[t] = f2b(v);
        } else if (idx < T1 + T2 + T3) {
            int t = idx - T1 - T2;
            int n = t >> 9, k = t & 511;
            wot[t] = f2b(w_out[k * 512 + n]);
        } else {
            int t = idx - T1 - T2 - T3;
            wkt[t] = f2b(wk_ret[t]);       // identity copy (row-major B^T)
        }
    }
}

// ---------------------------------------------------------------------------
// K1: projection GEMM  C[4096][1664] = xb @ wt^T, epilogue scatters into
//     qs/ks/rqb  (bf16[b][s][n][64], q's pre-scaled by DH^-0.5 * log2e)
//     and vt (bf16[b][128][n], transposed V).
// grid (64, 26), 256 threads (4 waves x 16 rows, 64 cols/block)
// ---------------------------------------------------------------------------
__global__ __launch_bounds__(256) void k_proj(const unsigned short* __restrict__ xb,
                                              const unsigned short* __restrict__ wt,
                                              unsigned short* __restrict__ qs,
                                              unsigned short* __restrict__ ks,
                                              unsigned short* __restrict__ rqb,
                                              unsigned short* __restrict__ vt)
{
    const int lane = threadIdx.x & 63, wid = threadIdx.x >> 6;
    const int lr = lane & 15, lg = lane >> 4;
    const int row0 = blockIdx.x * 64 + wid * 16;
    const int col0 = blockIdx.y * 64;

    const f32x4 z = {0.f, 0.f, 0.f, 0.f};
    f32x4 acc[4];
#pragma unroll
    for (int ct = 0; ct < 4; ++ct) acc[ct] = z;

    const unsigned short* ap = xb + (row0 + lr) * 512 + lg * 8;
#pragma unroll 4
    for (int k0 = 0; k0 < 512; k0 += 32) {
        bf16x8 a = *(const bf16x8*)(ap + k0);
#pragma unroll
        for (int ct = 0; ct < 4; ++ct) {
            bf16x8 b = *(const bf16x8*)(wt + (col0 + ct * 16 + lr) * 512 + k0 + lg * 8);
            acc[ct] = mfma16(a, b, acc[ct]);
        }
    }

#pragma unroll
    for (int ct = 0; ct < 4; ++ct) {
#pragma unroll
        for (int i = 0; i < 4; ++i) {
            int gr = row0 + lg * 4 + i;          // 0..4095
            int gc = col0 + ct * 16 + lr;        // 0..1663
            float v = acc[ct][i];
            int b = gr >> 11, in = gr & 2047;
            if (gc < 512) {
                int s = gc >> 6, d = gc & 63;
                qs[((b * 8 + s) * 2048 + in) * 64 + d] = f2b(v * SCALE_L2E);
            } else if (gc < 1024) {
                int c = gc - 512; int s = c >> 6, d = c & 63;
                ks[((b * 8 + s) * 2048 + in) * 64 + d] = f2b(v);
            } else if (gc < 1152) {
                int c = gc - 1024;               // 0..127 = r*64+d
                vt[(b * 128 + c) * 2048 + in] = f2b(v);
            } else {
                int c = gc - 1152; int s = c >> 6, d = c & 63;
                rqb[((b * 8 + s) * 2048 + in) * 64 + d] = f2b(v * SCALE_L2E);
            }
        }
    }
}

// ---------------------------------------------------------------------------
// K2: flash attention (stage 1) + fused retrieval composition (stage 2).
// R7: cooperative LDS staging. grid 512 = (b*s)[16] x qtile64[32]; 4 waves,
// wave w owns q-rows w*16..+16; ALL waves share each staged K/V tile.
// Per KV-tile (64 keys): K tile 64x64 (8KB) + V tile 128x64 (16KB) staged
// via global_load_lds width-16 (coalesced, 24 instrs/block), double-buffered.
// LDS rows are 128B (= bank wrap) so reads XOR-swizzle the 16B chunk index
// with (row&7); the stage pre-applies the same XOR on the GLOBAL source
// (rule #21: linear dest + inverse-swizzled source + swizzled read).
// ---------------------------------------------------------------------------
__global__ __launch_bounds__(256, 2) void k_attn(const unsigned short* __restrict__ qs,
                                                 const unsigned short* __restrict__ ks,
                                                 const unsigned short* __restrict__ rqb,
                                                 const unsigned short* __restrict__ vt,
                                                 const unsigned short* __restrict__ wkt,
                                                 unsigned short* __restrict__ ob)
{
    // kbuf[2]: 2 x 8KB @ 0, 8192 ; vbuf[2]: 2 x 16KB @ 16384, 32768
    __shared__ unsigned char kv_lds[49152];
    __shared__ unsigned short p_lds[4][16][72];       // 9.2 KB (pad 64->72)

    const int tid = threadIdx.x;
    const int lane = tid & 63, wid = tid >> 6;
    const int lr = lane & 15, lg = lane >> 4;
    const int bid = blockIdx.x;
    const int bs = bid >> 5, qt = bid & 31;           // bs = b*8+s
    const int gb = bs >> 3, gs = bs & 7;
    const int qrow0 = qt * 64 + wid * 16;

    const int sub = lane >> 3;                        // 0..7 (row within 8-row stripe)
    const int chk = lane & 7;                         // 16B chunk slot
    const int scs = chk ^ sub;                        // swizzled source chunk
    const int swz = lr & 7;                           // read-side XOR

    // Q fragments, kept in registers for the whole main loop
    const unsigned short* qbase = qs + ((size_t)bs * 2048 + qrow0 + lr) * 64 + lg * 8;
    const bf16x8 q0 = *(const bf16x8*)(qbase);
    const bf16x8 q1 = *(const bf16x8*)(qbase + 32);

    const unsigned short* kbase = ks + (size_t)bs * 131072;     // [2048][64]
    const unsigned short* vbase = vt + (size_t)gb * 262144;     // [128][2048]

    const f32x4 z = {0.f, 0.f, 0.f, 0.f};
    bf16x8 ones;
#pragma unroll
    for (int j = 0; j < 8; ++j) ones[j] = (short)0x3F80;

    float m_r[4];
    f32x4 acc[8];
    f32x4 acc_l = z;
#pragma unroll
    for (int i = 0; i < 4; ++i) m_r[i] = -3.0e38f;
#pragma unroll
    for (int c8 = 0; c8 < 8; ++c8) acc[c8] = z;

    // ---- stage helper (6 instrs per wave per tile) as a lambda
    auto STAGE = [&](int buf, int k0) {
        unsigned char* kb = kv_lds + buf * 8192;
        unsigned char* vb = kv_lds + 16384 + buf * 16384;
        // K rows wid*16 .. +16 (2 x 8 rows)
#pragma unroll
        for (int ii = 0; ii < 2; ++ii) {
            int r0 = wid * 16 + ii * 8;
            const unsigned short* g = kbase + (size_t)(k0 + r0 + sub) * 64 + scs * 8;
            stage16(g, kb + r0 * 128);
        }
        // V rows wid*32 .. +32 (4 x 8 rows)
#pragma unroll
        for (int ii = 0; ii < 4; ++ii) {
            int r0 = wid * 32 + ii * 8;
            const unsigned short* g = vbase + (size_t)(r0 + sub) * 2048 + k0 + scs * 8;
            stage16(g, vb + r0 * 128);
        }
    };

    STAGE(0, 0);                                      // prologue: tile 0

    for (int kt = 0; kt < 32; ++kt) {
        const int cur = kt & 1;
        if (kt != 31) STAGE(cur ^ 1, (kt + 1) * 64);  // async prefetch next tile
        if (kt != 31) { asm volatile("s_waitcnt vmcnt(6)" ::: "memory"); }
        else          { asm volatile("s_waitcnt vmcnt(0)" ::: "memory"); }
        __syncthreads();                              // all waves' cur-tile stage done

        const unsigned char* kb = kv_lds + cur * 8192;
        const unsigned char* vb = kv_lds + 16384 + cur * 16384;

        // --- S = Q K^T (16 x 64 tile) from LDS (swizzled reads)
        f32x4 s[4];
#pragma unroll
        for (int ct = 0; ct < 4; ++ct) {
            const unsigned char* kr = kb + (ct * 16 + lr) * 128;
            bf16x8 kf0 = *(const bf16x8*)(kr + ((lg ^ swz) << 4));
            bf16x8 kf1 = *(const bf16x8*)(kr + (((lg + 4) ^ swz) << 4));
            f32x4 t = z;
            t = mfma16(q0, kf0, t);
            t = mfma16(q1, kf1, t);
            s[ct] = t;
        }

        // --- deferred-max online softmax (log2 units)
        float lm[4];
        bool need = false;
#pragma unroll
        for (int i = 0; i < 4; ++i) {
            lm[i] = fmaxf(fmaxf(s[0][i], s[1][i]), fmaxf(s[2][i], s[3][i]));
            need = need || (lm[i] > m_r[i] + 8.0f);
        }
        if (__any(need)) {
#pragma unroll
            for (int i = 0; i < 4; ++i) {
                float mx = lm[i];
                mx = fmaxf(mx, __shfl_xor(mx, 1, 16));
                mx = fmaxf(mx, __shfl_xor(mx, 2, 16));
                mx = fmaxf(mx, __shfl_xor(mx, 4, 16));
                mx = fmaxf(mx, __shfl_xor(mx, 8, 16));
                float m_new = fmaxf(m_r[i], mx);
                float alpha = exp2f(m_r[i] - m_new);
#pragma unroll
                for (int c8 = 0; c8 < 8; ++c8) acc[c8][i] *= alpha;
                acc_l[i] *= alpha;
                m_r[i] = m_new;
            }
        }
        // --- P = exp2(S - m), bf16, through wave-private LDS tile
#pragma unroll
        for (int i = 0; i < 4; ++i) {
#pragma unroll
            for (int ct = 0; ct < 4; ++ct)
                p_lds[wid][lg * 4 + i][ct * 16 + lr] = f2b_hw(exp2f(s[ct][i] - m_r[i]));
        }
        bf16x8 pf0 = *(const bf16x8*)(&p_lds[wid][lr][lg * 8]);
        bf16x8 pf1 = *(const bf16x8*)(&p_lds[wid][lr][32 + lg * 8]);

        // --- PV from LDS V tile (+ row-sum via ones-column)
#pragma unroll
        for (int c8 = 0; c8 < 8; ++c8) {
            const unsigned char* vr = vb + (c8 * 16 + lr) * 128;
            bf16x8 vf0 = *(const bf16x8*)(vr + ((lg ^ swz) << 4));
            bf16x8 vf1 = *(const bf16x8*)(vr + (((lg + 4) ^ swz) << 4));
            acc[c8] = mfma16(pf0, vf0, acc[c8]);
            acc[c8] = mfma16(pf1, vf1, acc[c8]);
        }
        acc_l = mfma16(pf0, ones, acc_l);
        acc_l = mfma16(pf1, ones, acc_l);

        __syncthreads();                              // reads of buf[cur] done
    }

    // --- epilogue: every wave holds full 2048-key state for its 16 rows
    float inv[4];
#pragma unroll
    for (int i = 0; i < 4; ++i) inv[i] = 1.0f / acc_l[i];

    // rq fragments (pre-scaled by DH^-0.5*log2e in k_proj)
    const unsigned short* rqbase = rqb + ((size_t)bs * 2048 + qrow0 + lr) * 64 + lg * 8;
    const bf16x8 rq0 = *(const bf16x8*)(rqbase);
    const bf16x8 rq1 = *(const bf16x8*)(rqbase + 32);

    // stage 2 via MFMA: T[q][d] = sum_dp rq[q][dp] * wk_ret[d][dp]
    f32x4 Tt[4];
#pragma unroll
    for (int ct = 0; ct < 4; ++ct) {
        bf16x8 wb0 = *(const bf16x8*)(wkt + (ct * 16 + lr) * 64 + lg * 8);
        bf16x8 wb1 = *(const bf16x8*)(wkt + (ct * 16 + lr) * 64 + 32 + lg * 8);
        f32x4 t = z;
        t = mfma16(rq0, wb0, t);
        t = mfma16(rq1, wb1, t);
        Tt[ct] = t;
    }

    // sim_r[row] = sum_{d} T[row][d] * retrN[row][r*64+d]   (log2 units)
    float w0v[4], w1v[4];
#pragma unroll
    for (int i = 0; i < 4; ++i) {
        float s0 = 0.f, s1 = 0.f;
#pragma unroll
        for (int ct = 0; ct < 4; ++ct) {
            s0 += Tt[ct][i] * acc[ct][i];
            s1 += Tt[ct][i] * acc[4 + ct][i];
        }
        s0 *= inv[i]; s1 *= inv[i];
        s0 += __shfl_xor(s0, 1, 16); s1 += __shfl_xor(s1, 1, 16);
        s0 += __shfl_xor(s0, 2, 16); s1 += __shfl_xor(s1, 2, 16);
        s0 += __shfl_xor(s0, 4, 16); s1 += __shfl_xor(s1, 4, 16);
        s0 += __shfl_xor(s0, 8, 16); s1 += __shfl_xor(s1, 8, 16);
        float mm = fmaxf(s0, s1);
        float e0 = exp2f(s0 - mm), e1 = exp2f(s1 - mm);
        float inw = 1.0f / (e0 + e1);
        w0v[i] = e0 * inw; w1v[i] = e1 * inw;
    }

    // --- combine r=2 and store ob[b][n][gs*64 + d]
#pragma unroll
    for (int ct = 0; ct < 4; ++ct) {
#pragma unroll
        for (int i = 0; i < 4; ++i) {
            float o = (w0v[i] * acc[ct][i] + w1v[i] * acc[4 + ct][i]) * inv[i];
            ob[((size_t)gb * 2048 + qrow0 + lg * 4 + i) * 512 + gs * 64 + ct * 16 + lr] = f2b_hw(o);
        }
    }
}

// ---------------------------------------------------------------------------
// K3: final GEMM  out[4096][512] (fp32) = ob(bf16) @ w_out, via wot = w_out^T
// grid (64, 8), 256 threads
// ---------------------------------------------------------------------------
__global__ __launch_bounds__(256) void k_out(const unsigned short* __restrict__ ob,
                                             const unsigned short* __restrict__ wot,
                                             float* __restrict__ out)
{
    const int lane = threadIdx.x & 63, wid = threadIdx.x >> 6;
    const int lr = lane & 15, lg = lane >> 4;
    const int row0 = blockIdx.x * 64 + wid * 16;
    const int col0 = blockIdx.y * 64;

    const f32x4 z = {0.f, 0.f, 0.f, 0.f};
    f32x4 acc[4];
#pragma unroll
    for (int ct = 0; ct < 4; ++ct) acc[ct] = z;

    const unsigned short* ap = ob + (row0 + lr) * 512 + lg * 8;
#pragma unroll 4
    for (int k0 = 0; k0 < 512; k0 += 32) {
        bf16x8 a = *(const bf16x8*)(ap + k0);
#pragma unroll
        for (int ct = 0; ct < 4; ++ct) {
            bf16x8 b = *(const bf16x8*)(wot + (col0 + ct * 16 + lr) * 512 + k0 + lg * 8);
            acc[ct] = mfma16(a, b, acc[ct]);
        }
    }
#pragma unroll
    for (int ct = 0; ct < 4; ++ct)
#pragma unroll
        for (int i = 0; i < 4; ++i)
            out[(size_t)(row0 + lg * 4 + i) * 512 + col0 + ct * 16 + lr] = acc[ct][i];
}

// ---------------------------------------------------------------------------
extern "C" void kernel_launch(void* const* d_in, const int* in_sizes, int n_in,
                              void* d_out, int out_size, void* d_ws, size_t ws_size,
                              hipStream_t stream)
{
    (void)in_sizes; (void)n_in; (void)out_size; (void)ws_size;
    const float* x      = (const float*)d_in[0];
    const float* wq_s   = (const float*)d_in[1];
    const float* wk_s   = (const float*)d_in[2];
    const float* wv_r   = (const float*)d_in[3];
    const float* wq_r   = (const float*)d_in[4];
    const float* wk_ret = (const float*)d_in[5];
    const float* w_out  = (const float*)d_in[6];

    char* ws = (char*)d_ws;                            // needs ~24.3 MB
    unsigned short* xb  = (unsigned short*)(ws + 0);          // [4096][512]
    unsigned short* wt  = (unsigned short*)(ws + 4194304);    // [1664][512]
    unsigned short* qsb = (unsigned short*)(ws + 5898240);    // [2][8][2048][64]
    unsigned short* ksb = (unsigned short*)(ws + 10092544);   // [2][8][2048][64]
    unsigned short* rqb = (unsigned short*)(ws + 14286848);   // [2][8][2048][64]
    unsigned short* vtb = (unsigned short*)(ws + 18481152);   // [2][128][2048]
    unsigned short* obb = (unsigned short*)(ws + 19529728);   // [2][2048][512]
    unsigned short* wot = (unsigned short*)(ws + 23724032);   // [512][512]
    unsigned short* wkt = (unsigned short*)(ws + 24248320);   // [64][64]

    hipLaunchKernelGGL(k_convert, dim3(2048), dim3(256), 0, stream,
                       x, wq_s, wk_s, wv_r, wq_r, wk_ret, w_out, xb, wt, wot, wkt);
    hipLaunchKernelGGL(k_proj, dim3(64, 26), dim3(256), 0, stream,
                       xb, wt, qsb, ksb, rqb, vtb);
    hipLaunchKernelGGL(k_attn, dim3(512), dim3(256), 0, stream,
                       qsb, ksb, rqb, vtb, wkt, obb);
    hipLaunchKernelGGL(k_out, dim3(64, 8), dim3(256), 0, stream,
                       obb, wot, (float*)d_out);
}

// Round 8
// 96.927 us; speedup vs baseline: 4.4044x; 1.6089x over previous
//
#include <hip/hip_runtime.h>
#include <hip/hip_bf16.h>

#define DEV __device__ __forceinline__

typedef __attribute__((ext_vector_type(8))) short bf16x8;
typedef __attribute__((ext_vector_type(4))) float f32x4;

DEV float b2f(unsigned short u) {
    unsigned int v = ((unsigned int)u) << 16;
    float f; __builtin_memcpy(&f, &v, 4); return f;
}
DEV unsigned short f2b(float f) {            // RNE via bit-ops
    unsigned int v; __builtin_memcpy(&v, &f, 4);
    v = (v + 0x7fffu + ((v >> 16) & 1u)) >> 16;
    return (unsigned short)v;
}
DEV unsigned short f2b_hw(float f) {         // hardware cvt (RNE)
    __hip_bfloat16 h = __float2bfloat16(f);
    unsigned short u; __builtin_memcpy(&u, &h, 2); return u;
}

DEV f32x4 mfma16(bf16x8 a, bf16x8 b, f32x4 c) {
    return __builtin_amdgcn_mfma_f32_16x16x32_bf16(a, b, c, 0, 0, 0);
}

// global -> LDS async copy, 16B per lane; lds dest = uniform base + lane*16
DEV void stage16(const void* g, void* l) {
    __builtin_amdgcn_global_load_lds((const __attribute__((address_space(1))) void*)g,
                                     (__attribute__((address_space(3))) void*)l, 16, 0, 0);
}

constexpr float SCALE_L2E = 0.125f * 1.44269504088896340736f;  // DH^-0.5 * log2(e)

// ---------------------------------------------------------------------------
// K0: fp32 -> bf16 conversions.
//  xb[4096][512]  = x
//  wt[1664][512]  = [wq_s | wk_s | wv_r | wq_r]^T  (B^T form for MFMA)
//  wot[512][512]  = w_out^T
//  wkt[64][64]    = wk_ret ROW-MAJOR (B^T form for T = RQ @ wk_ret^T)
// ---------------------------------------------------------------------------
__global__ void k_convert(const float* __restrict__ x,
                          const float* __restrict__ wq_s, const float* __restrict__ wk_s,
                          const float* __restrict__ wv_r, const float* __restrict__ wq_r,
                          const float* __restrict__ wk_ret, const float* __restrict__ w_out,
                          unsigned short* __restrict__ xb,
                          unsigned short* __restrict__ wt,
                          unsigned short* __restrict__ wot,
                          unsigned short* __restrict__ wkt)
{
    const int T1 = 4096 * 512;
    const int T2 = 1664 * 512;
    const int T3 = 512 * 512;
    const int T4 = 64 * 64;
    const int total = T1 + T2 + T3 + T4;
    for (int idx = blockIdx.x * blockDim.x + threadIdx.x; idx < total;
         idx += gridDim.x * blockDim.x) {
        if (idx < T1) {
            xb[idx] = f2b(x[idx]);
        } else if (idx < T1 + T2) {
            int t = idx - T1;
            int n = t >> 9, k = t & 511;   // t == n*512 + k
            float v;
            if (n < 512)       v = wq_s[k * 512 + n];
            else if (n < 1024) v = wk_s[k * 512 + (n - 512)];
            else if (n < 1152) v = wv_r[k * 128 + (n - 1024)];
            else               v = wq_r[k * 512 + (n - 1152)];
            wt[t] = f2b(v);
        } else if (idx < T1 + T2 + T3) {
            int t = idx - T1 - T2;
            int n = t >> 9, k = t & 511;
            wot[t] = f2b(w_out[k * 512 + n]);
        } else {
            int t = idx - T1 - T2 - T3;
            wkt[t] = f2b(wk_ret[t]);       // identity copy (row-major B^T)
        }
    }
}

// ---------------------------------------------------------------------------
// K1/K3: staged GEMM  C[4096][N*] = A(bf16 [4096][512]) @ Bt(bf16 [N][512])^T
// BM=128, BN=64, BK=64; 4 waves 2x2, wave (wr,wc) owns 64x32 of C.
// Staging identical to k_attn's proven pattern: global_load_lds width-16,
// linear LDS dest, inverse-swizzled global source chunk (chk^sub), XOR-
// swizzled ds_read_b128, double-buffered, vmcnt(6) one-tile-ahead.
// EPI=0: scatter epilogue into qs/ks/rqb/vt (projection).
// EPI=1: fp32 store epilogue (final output GEMM).
// ---------------------------------------------------------------------------
template<int EPI>
__global__ __launch_bounds__(256, 2) void k_gemm(const unsigned short* __restrict__ A,
                                                 const unsigned short* __restrict__ Bt,
                                                 unsigned short* __restrict__ qs,
                                                 unsigned short* __restrict__ ks,
                                                 unsigned short* __restrict__ rqb,
                                                 unsigned short* __restrict__ vt,
                                                 float* __restrict__ out)
{
    // A bufs: 2 x 16KB @ 0,16384 ; B bufs: 2 x 8KB @ 32768,40960
    __shared__ unsigned char ab_lds[49152];

    const int tid = threadIdx.x;
    const int lane = tid & 63, wid = tid >> 6;
    const int lr = lane & 15, lg = lane >> 4;
    const int wr = wid >> 1, wc = wid & 1;
    const int brow0 = blockIdx.x * 128;
    const int bcol0 = blockIdx.y * 64;

    const int sub = lane >> 3;            // row within 8-row stripe
    const int chk = lane & 7;             // 16B chunk slot
    const int scs = chk ^ sub;            // swizzled source chunk
    const int swz = lr & 7;               // read-side XOR

    const f32x4 z = {0.f, 0.f, 0.f, 0.f};
    f32x4 acc[4][2];
#pragma unroll
    for (int m = 0; m < 4; ++m)
#pragma unroll
        for (int n = 0; n < 2; ++n) acc[m][n] = z;

    const unsigned short* Ab = A + (size_t)brow0 * 512;

    auto STAGE = [&](int buf, int k0) {
        unsigned char* ab = ab_lds + buf * 16384;
        unsigned char* bb = ab_lds + 32768 + buf * 8192;
        // A: 16 stripes of 8 rows; wave stages 4
#pragma unroll
        for (int ii = 0; ii < 4; ++ii) {
            int r0 = wid * 32 + ii * 8;
            const unsigned short* g = Ab + (size_t)(r0 + sub) * 512 + k0 + scs * 8;
            stage16(g, ab + r0 * 128);
        }
        // B: 8 stripes; wave stages 2
#pragma unroll
        for (int ii = 0; ii < 2; ++ii) {
            int r0 = wid * 16 + ii * 8;
            const unsigned short* g = Bt + (size_t)(bcol0 + r0 + sub) * 512 + k0 + scs * 8;
            stage16(g, bb + r0 * 128);
        }
    };

    STAGE(0, 0);

    for (int kt = 0; kt < 8; ++kt) {
        const int cur = kt & 1;
        if (kt != 7) STAGE(cur ^ 1, (kt + 1) * 64);
        if (kt != 7) { asm volatile("s_waitcnt vmcnt(6)" ::: "memory"); }
        else         { asm volatile("s_waitcnt vmcnt(0)" ::: "memory"); }
        __syncthreads();

        const unsigned char* ab = ab_lds + cur * 16384;
        const unsigned char* bb = ab_lds + 32768 + cur * 8192;

#pragma unroll
        for (int ksb = 0; ksb < 2; ++ksb) {
            const int c = ksb * 4 + lg;                       // k-chunk 0..7
            bf16x8 bfr[2];
#pragma unroll
            for (int n = 0; n < 2; ++n) {
                int row = wc * 32 + n * 16 + lr;
                bfr[n] = *(const bf16x8*)(bb + row * 128 + ((c ^ (row & 7)) << 4));
            }
#pragma unroll
            for (int m = 0; m < 4; ++m) {
                int row = wr * 64 + m * 16 + lr;
                bf16x8 af = *(const bf16x8*)(ab + row * 128 + ((c ^ (row & 7)) << 4));
                acc[m][0] = mfma16(af, bfr[0], acc[m][0]);
                acc[m][1] = mfma16(af, bfr[1], acc[m][1]);
            }
        }
        __syncthreads();
    }

    // --- epilogue: C row = brow0+wr*64+m*16+lg*4+i, col = bcol0+wc*32+n*16+lr
#pragma unroll
    for (int m = 0; m < 4; ++m) {
#pragma unroll
        for (int n = 0; n < 2; ++n) {
#pragma unroll
            for (int i = 0; i < 4; ++i) {
                int gr = brow0 + wr * 64 + m * 16 + lg * 4 + i;
                int gc = bcol0 + wc * 32 + n * 16 + lr;
                float v = acc[m][n][i];
                if (EPI == 1) {
                    out[(size_t)gr * 512 + gc] = v;
                } else {
                    int b = gr >> 11, in = gr & 2047;
                    if (gc < 512) {
                        int s = gc >> 6, d = gc & 63;
                        qs[((b * 8 + s) * 2048 + in) * 64 + d] = f2b(v * SCALE_L2E);
                    } else if (gc < 1024) {
                        int cgc = gc - 512; int s = cgc >> 6, d = cgc & 63;
                        ks[((b * 8 + s) * 2048 + in) * 64 + d] = f2b(v);
                    } else if (gc < 1152) {
                        int cgc = gc - 1024;             // 0..127 = r*64+d
                        vt[(b * 128 + cgc) * 2048 + in] = f2b(v);
                    } else {
                        int cgc = gc - 1152; int s = cgc >> 6, d = cgc & 63;
                        rqb[((b * 8 + s) * 2048 + in) * 64 + d] = f2b(v * SCALE_L2E);
                    }
                }
            }
        }
    }
}

// ---------------------------------------------------------------------------
// K2: flash attention (stage 1) + fused retrieval composition (stage 2).
// R7 structure (unchanged): cooperative LDS staging, grid 512, 4 waves.
// ---------------------------------------------------------------------------
__global__ __launch_bounds__(256, 2) void k_attn(const unsigned short* __restrict__ qs,
                                                 const unsigned short* __restrict__ ks,
                                                 const unsigned short* __restrict__ rqb,
                                                 const unsigned short* __restrict__ vt,
                                                 const unsigned short* __restrict__ wkt,
                                                 unsigned short* __restrict__ ob)
{
    // kbuf[2]: 2 x 8KB @ 0, 8192 ; vbuf[2]: 2 x 16KB @ 16384, 32768
    __shared__ unsigned char kv_lds[49152];
    __shared__ unsigned short p_lds[4][16][72];       // 9.2 KB (pad 64->72)

    const int tid = threadIdx.x;
    const int lane = tid & 63, wid = tid >> 6;
    const int lr = lane & 15, lg = lane >> 4;
    const int bid = blockIdx.x;
    const int bs = bid >> 5, qt = bid & 31;           // bs = b*8+s
    const int gb = bs >> 3, gs = bs & 7;
    const int qrow0 = qt * 64 + wid * 16;

    const int sub = lane >> 3;                        // 0..7 (row within 8-row stripe)
    const int chk = lane & 7;                         // 16B chunk slot
    const int scs = chk ^ sub;                        // swizzled source chunk
    const int swz = lr & 7;                           // read-side XOR

    // Q fragments, kept in registers for the whole main loop
    const unsigned short* qbase = qs + ((size_t)bs * 2048 + qrow0 + lr) * 64 + lg * 8;
    const bf16x8 q0 = *(const bf16x8*)(qbase);
    const bf16x8 q1 = *(const bf16x8*)(qbase + 32);

    const unsigned short* kbase = ks + (size_t)bs * 131072;     // [2048][64]
    const unsigned short* vbase = vt + (size_t)gb * 262144;     // [128][2048]

    const f32x4 z = {0.f, 0.f, 0.f, 0.f};
    bf16x8 ones;
#pragma unroll
    for (int j = 0; j < 8; ++j) ones[j] = (short)0x3F80;

    float m_r[4];
    f32x4 acc[8];
    f32x4 acc_l = z;
#pragma unroll
    for (int i = 0; i < 4; ++i) m_r[i] = -3.0e38f;
#pragma unroll
    for (int c8 = 0; c8 < 8; ++c8) acc[c8] = z;

    auto STAGE = [&](int buf, int k0) {
        unsigned char* kb = kv_lds + buf * 8192;
        unsigned char* vb = kv_lds + 16384 + buf * 16384;
#pragma unroll
        for (int ii = 0; ii < 2; ++ii) {
            int r0 = wid * 16 + ii * 8;
            const unsigned short* g = kbase + (size_t)(k0 + r0 + sub) * 64 + scs * 8;
            stage16(g, kb + r0 * 128);
        }
#pragma unroll
        for (int ii = 0; ii < 4; ++ii) {
            int r0 = wid * 32 + ii * 8;
            const unsigned short* g = vbase + (size_t)(r0 + sub) * 2048 + k0 + scs * 8;
            stage16(g, vb + r0 * 128);
        }
    };

    STAGE(0, 0);                                      // prologue: tile 0

    for (int kt = 0; kt < 32; ++kt) {
        const int cur = kt & 1;
        if (kt != 31) STAGE(cur ^ 1, (kt + 1) * 64);  // async prefetch next tile
        if (kt != 31) { asm volatile("s_waitcnt vmcnt(6)" ::: "memory"); }
        else          { asm volatile("s_waitcnt vmcnt(0)" ::: "memory"); }
        __syncthreads();                              // all waves' cur-tile stage done

        const unsigned char* kb = kv_lds + cur * 8192;
        const unsigned char* vb = kv_lds + 16384 + cur * 16384;

        // --- S = Q K^T (16 x 64 tile) from LDS (swizzled reads)
        f32x4 s[4];
#pragma unroll
        for (int ct = 0; ct < 4; ++ct) {
            const unsigned char* kr = kb + (ct * 16 + lr) * 128;
            bf16x8 kf0 = *(const bf16x8*)(kr + ((lg ^ swz) << 4));
            bf16x8 kf1 = *(const bf16x8*)(kr + (((lg + 4) ^ swz) << 4));
            f32x4 t = z;
            t = mfma16(q0, kf0, t);
            t = mfma16(q1, kf1, t);
            s[ct] = t;
        }

        // --- deferred-max online softmax (log2 units)
        float lm[4];
        bool need = false;
#pragma unroll
        for (int i = 0; i < 4; ++i) {
            lm[i] = fmaxf(fmaxf(s[0][i], s[1][i]), fmaxf(s[2][i], s[3][i]));
            need = need || (lm[i] > m_r[i] + 8.0f);
        }
        if (__any(need)) {
#pragma unroll
            for (int i = 0; i < 4; ++i) {
                float mx = lm[i];
                mx = fmaxf(mx, __shfl_xor(mx, 1, 16));
                mx = fmaxf(mx, __shfl_xor(mx, 2, 16));
                mx = fmaxf(mx, __shfl_xor(mx, 4, 16));
                mx = fmaxf(mx, __shfl_xor(mx, 8, 16));
                float m_new = fmaxf(m_r[i], mx);
                float alpha = exp2f(m_r[i] - m_new);
#pragma unroll
                for (int c8 = 0; c8 < 8; ++c8) acc[c8][i] *= alpha;
                acc_l[i] *= alpha;
                m_r[i] = m_new;
            }
        }
        // --- P = exp2(S - m), bf16, through wave-private LDS tile
#pragma unroll
        for (int i = 0; i < 4; ++i) {
#pragma unroll
            for (int ct = 0; ct < 4; ++ct)
                p_lds[wid][lg * 4 + i][ct * 16 + lr] = f2b_hw(exp2f(s[ct][i] - m_r[i]));
        }
        bf16x8 pf0 = *(const bf16x8*)(&p_lds[wid][lr][lg * 8]);
        bf16x8 pf1 = *(const bf16x8*)(&p_lds[wid][lr][32 + lg * 8]);

        // --- PV from LDS V tile (+ row-sum via ones-column)
#pragma unroll
        for (int c8 = 0; c8 < 8; ++c8) {
            const unsigned char* vr = vb + (c8 * 16 + lr) * 128;
            bf16x8 vf0 = *(const bf16x8*)(vr + ((lg ^ swz) << 4));
            bf16x8 vf1 = *(const bf16x8*)(vr + (((lg + 4) ^ swz) << 4));
            acc[c8] = mfma16(pf0, vf0, acc[c8]);
            acc[c8] = mfma16(pf1, vf1, acc[c8]);
        }
        acc_l = mfma16(pf0, ones, acc_l);
        acc_l = mfma16(pf1, ones, acc_l);

        __syncthreads();                              // reads of buf[cur] done
    }

    // --- epilogue: every wave holds full 2048-key state for its 16 rows
    float inv[4];
#pragma unroll
    for (int i = 0; i < 4; ++i) inv[i] = 1.0f / acc_l[i];

    // rq fragments (pre-scaled by DH^-0.5*log2e in k_proj)
    const unsigned short* rqbase = rqb + ((size_t)bs * 2048 + qrow0 + lr) * 64 + lg * 8;
    const bf16x8 rq0 = *(const bf16x8*)(rqbase);
    const bf16x8 rq1 = *(const bf16x8*)(rqbase + 32);

    // stage 2 via MFMA: T[q][d] = sum_dp rq[q][dp] * wk_ret[d][dp]
    f32x4 Tt[4];
#pragma unroll
    for (int ct = 0; ct < 4; ++ct) {
        bf16x8 wb0 = *(const bf16x8*)(wkt + (ct * 16 + lr) * 64 + lg * 8);
        bf16x8 wb1 = *(const bf16x8*)(wkt + (ct * 16 + lr) * 64 + 32 + lg * 8);
        f32x4 t = z;
        t = mfma16(rq0, wb0, t);
        t = mfma16(rq1, wb1, t);
        Tt[ct] = t;
    }

    // sim_r[row] = sum_{d} T[row][d] * retrN[row][r*64+d]   (log2 units)
    float w0v[4], w1v[4];
#pragma unroll
    for (int i = 0; i < 4; ++i) {
        float s0 = 0.f, s1 = 0.f;
#pragma unroll
        for (int ct = 0; ct < 4; ++ct) {
            s0 += Tt[ct][i] * acc[ct][i];
            s1 += Tt[ct][i] * acc[4 + ct][i];
        }
        s0 *= inv[i]; s1 *= inv[i];
        s0 += __shfl_xor(s0, 1, 16); s1 += __shfl_xor(s1, 1, 16);
        s0 += __shfl_xor(s0, 2, 16); s1 += __shfl_xor(s1, 2, 16);
        s0 += __shfl_xor(s0, 4, 16); s1 += __shfl_xor(s1, 4, 16);
        s0 += __shfl_xor(s0, 8, 16); s1 += __shfl_xor(s1, 8, 16);
        float mm = fmaxf(s0, s1);
        float e0 = exp2f(s0 - mm), e1 = exp2f(s1 - mm);
        float inw = 1.0f / (e0 + e1);
        w0v[i] = e0 * inw; w1v[i] = e1 * inw;
    }

    // --- combine r=2 and store ob[b][n][gs*64 + d]
#pragma unroll
    for (int ct = 0; ct < 4; ++ct) {
#pragma unroll
        for (int i = 0; i < 4; ++i) {
            float o = (w0v[i] * acc[ct][i] + w1v[i] * acc[4 + ct][i]) * inv[i];
            ob[((size_t)gb * 2048 + qrow0 + lg * 4 + i) * 512 + gs * 64 + ct * 16 + lr] = f2b_hw(o);
        }
    }
}

// ---------------------------------------------------------------------------
extern "C" void kernel_launch(void* const* d_in, const int* in_sizes, int n_in,
                              void* d_out, int out_size, void* d_ws, size_t ws_size,
                              hipStream_t stream)
{
    (void)in_sizes; (void)n_in; (void)out_size; (void)ws_size;
    const float* x      = (const float*)d_in[0];
    const float* wq_s   = (const float*)d_in[1];
    const float* wk_s   = (const float*)d_in[2];
    const float* wv_r   = (const float*)d_in[3];
    const float* wq_r   = (const float*)d_in[4];
    const float* wk_ret = (const float*)d_in[5];
    const float* w_out  = (const float*)d_in[6];

    char* ws = (char*)d_ws;                            // needs ~24.3 MB
    unsigned short* xb  = (unsigned short*)(ws + 0);          // [4096][512]
    unsigned short* wt  = (unsigned short*)(ws + 4194304);    // [1664][512]
    unsigned short* qsb = (unsigned short*)(ws + 5898240);    // [2][8][2048][64]
    unsigned short* ksb = (unsigned short*)(ws + 10092544);   // [2][8][2048][64]
    unsigned short* rqb = (unsigned short*)(ws + 14286848);   // [2][8][2048][64]
    unsigned short* vtb = (unsigned short*)(ws + 18481152);   // [2][128][2048]
    unsigned short* obb = (unsigned short*)(ws + 19529728);   // [2][2048][512]
    unsigned short* wot = (unsigned short*)(ws + 23724032);   // [512][512]
    unsigned short* wkt = (unsigned short*)(ws + 24248320);   // [64][64]

    hipLaunchKernelGGL(k_convert, dim3(2048), dim3(256), 0, stream,
                       x, wq_s, wk_s, wv_r, wq_r, wk_ret, w_out, xb, wt, wot, wkt);
    hipLaunchKernelGGL((k_gemm<0>), dim3(32, 26), dim3(256), 0, stream,
                       xb, wt, qsb, ksb, rqb, vtb, (float*)nullptr);
    hipLaunchKernelGGL(k_attn, dim3(512), dim3(256), 0, stream,
                       qsb, ksb, rqb, vtb, wkt, obb);
    hipLaunchKernelGGL((k_gemm<1>), dim3(32, 8), dim3(256), 0, stream,
                       obb, wot, (unsigned short*)nullptr, (unsigned short*)nullptr,
                       (unsigned short*)nullptr, (unsigned short*)nullptr, (float*)d_out);
}

// Round 9
// 96.365 us; speedup vs baseline: 4.4301x; 1.0058x over previous
//
#include <hip/hip_runtime.h>
#include <hip/hip_bf16.h>

#define DEV __device__ __forceinline__

typedef __attribute__((ext_vector_type(8))) short bf16x8;
typedef __attribute__((ext_vector_type(4))) float f32x4;

DEV float b2f(unsigned short u) {
    unsigned int v = ((unsigned int)u) << 16;
    float f; __builtin_memcpy(&f, &v, 4); return f;
}
DEV unsigned short f2b(float f) {            // RNE via bit-ops
    unsigned int v; __builtin_memcpy(&v, &f, 4);
    v = (v + 0x7fffu + ((v >> 16) & 1u)) >> 16;
    return (unsigned short)v;
}
DEV unsigned short f2b_hw(float f) {         // hardware cvt (RNE)
    __hip_bfloat16 h = __float2bfloat16(f);
    unsigned short u; __builtin_memcpy(&u, &h, 2); return u;
}

DEV f32x4 mfma16(bf16x8 a, bf16x8 b, f32x4 c) {
    return __builtin_amdgcn_mfma_f32_16x16x32_bf16(a, b, c, 0, 0, 0);
}

// global -> LDS async copy, 16B per lane; lds dest = uniform base + lane*16
DEV void stage16(const void* g, void* l) {
    __builtin_amdgcn_global_load_lds((const __attribute__((address_space(1))) void*)g,
                                     (__attribute__((address_space(3))) void*)l, 16, 0, 0);
}

constexpr float SCALE_L2E = 0.125f * 1.44269504088896340736f;  // DH^-0.5 * log2(e)

// ---------------------------------------------------------------------------
// K0: fp32 -> bf16 conversions.
//  xb[4096][512]  = x
//  wt[1664][512]  = [wq_s | wk_s | wv_r | wq_r]^T  (B^T form for MFMA)
//  wot[512][512]  = w_out^T
//  wkt[64][64]    = wk_ret ROW-MAJOR (B^T form for T = RQ @ wk_ret^T)
// ---------------------------------------------------------------------------
__global__ void k_convert(const float* __restrict__ x,
                          const float* __restrict__ wq_s, const float* __restrict__ wk_s,
                          const float* __restrict__ wv_r, const float* __restrict__ wq_r,
                          const float* __restrict__ wk_ret, const float* __restrict__ w_out,
                          unsigned short* __restrict__ xb,
                          unsigned short* __restrict__ wt,
                          unsigned short* __restrict__ wot,
                          unsigned short* __restrict__ wkt)
{
    const int T1 = 4096 * 512;
    const int T2 = 1664 * 512;
    const int T3 = 512 * 512;
    const int T4 = 64 * 64;
    const int total = T1 + T2 + T3 + T4;
    for (int idx = blockIdx.x * blockDim.x + threadIdx.x; idx < total;
         idx += gridDim.x * blockDim.x) {
        if (idx < T1) {
            xb[idx] = f2b(x[idx]);
        } else if (idx < T1 + T2) {
            int t = idx - T1;
            int n = t >> 9, k = t & 511;   // t == n*512 + k
            float v;
            if (n < 512)       v = wq_s[k * 512 + n];
            else if (n < 1024) v = wk_s[k * 512 + (n - 512)];
            else if (n < 1152) v = wv_r[k * 128 + (n - 1024)];
            else               v = wq_r[k * 512 + (n - 1152)];
            wt[t] = f2b(v);
        } else if (idx < T1 + T2 + T3) {
            int t = idx - T1 - T2;
            int n = t >> 9, k = t & 511;
            wot[t] = f2b(w_out[k * 512 + n]);
        } else {
            int t = idx - T1 - T2 - T3;
            wkt[t] = f2b(wk_ret[t]);       // identity copy (row-major B^T)
        }
    }
}

// ---------------------------------------------------------------------------
// K1/K3: staged GEMM  C[4096][N*] = A(bf16 [4096][512]) @ Bt(bf16 [N][512])^T
// BM=128, BN=64, BK=64; 4 waves 2x2, wave (wr,wc) owns 64x32 of C.
// EPI=0: scatter epilogue into qs/ks/rqb/vt (projection).
// EPI=1: fp32 store epilogue (final output GEMM).
// ---------------------------------------------------------------------------
template<int EPI>
__global__ __launch_bounds__(256, 2) void k_gemm(const unsigned short* __restrict__ A,
                                                 const unsigned short* __restrict__ Bt,
                                                 unsigned short* __restrict__ qs,
                                                 unsigned short* __restrict__ ks,
                                                 unsigned short* __restrict__ rqb,
                                                 unsigned short* __restrict__ vt,
                                                 float* __restrict__ out)
{
    // A bufs: 2 x 16KB @ 0,16384 ; B bufs: 2 x 8KB @ 32768,40960
    __shared__ unsigned char ab_lds[49152];

    const int tid = threadIdx.x;
    const int lane = tid & 63, wid = tid >> 6;
    const int lr = lane & 15, lg = lane >> 4;
    const int wr = wid >> 1, wc = wid & 1;
    const int brow0 = blockIdx.x * 128;
    const int bcol0 = blockIdx.y * 64;

    const int sub = lane >> 3;            // row within 8-row stripe
    const int chk = lane & 7;             // 16B chunk slot
    const int scs = chk ^ sub;            // swizzled source chunk

    const f32x4 z = {0.f, 0.f, 0.f, 0.f};
    f32x4 acc[4][2];
#pragma unroll
    for (int m = 0; m < 4; ++m)
#pragma unroll
        for (int n = 0; n < 2; ++n) acc[m][n] = z;

    const unsigned short* Ab = A + (size_t)brow0 * 512;

    auto STAGE = [&](int buf, int k0) {
        unsigned char* ab = ab_lds + buf * 16384;
        unsigned char* bb = ab_lds + 32768 + buf * 8192;
#pragma unroll
        for (int ii = 0; ii < 4; ++ii) {
            int r0 = wid * 32 + ii * 8;
            const unsigned short* g = Ab + (size_t)(r0 + sub) * 512 + k0 + scs * 8;
            stage16(g, ab + r0 * 128);
        }
#pragma unroll
        for (int ii = 0; ii < 2; ++ii) {
            int r0 = wid * 16 + ii * 8;
            const unsigned short* g = Bt + (size_t)(bcol0 + r0 + sub) * 512 + k0 + scs * 8;
            stage16(g, bb + r0 * 128);
        }
    };

    STAGE(0, 0);

    for (int kt = 0; kt < 8; ++kt) {
        const int cur = kt & 1;
        if (kt != 7) STAGE(cur ^ 1, (kt + 1) * 64);
        if (kt != 7) { asm volatile("s_waitcnt vmcnt(6)" ::: "memory"); }
        else         { asm volatile("s_waitcnt vmcnt(0)" ::: "memory"); }
        __syncthreads();

        const unsigned char* ab = ab_lds + cur * 16384;
        const unsigned char* bb = ab_lds + 32768 + cur * 8192;

#pragma unroll
        for (int ksb = 0; ksb < 2; ++ksb) {
            const int c = ksb * 4 + lg;                       // k-chunk 0..7
            bf16x8 bfr[2];
#pragma unroll
            for (int n = 0; n < 2; ++n) {
                int row = wc * 32 + n * 16 + lr;
                bfr[n] = *(const bf16x8*)(bb + row * 128 + ((c ^ (row & 7)) << 4));
            }
#pragma unroll
            for (int m = 0; m < 4; ++m) {
                int row = wr * 64 + m * 16 + lr;
                bf16x8 af = *(const bf16x8*)(ab + row * 128 + ((c ^ (row & 7)) << 4));
                acc[m][0] = mfma16(af, bfr[0], acc[m][0]);
                acc[m][1] = mfma16(af, bfr[1], acc[m][1]);
            }
        }
        __syncthreads();
    }

    // --- epilogue: C row = brow0+wr*64+m*16+lg*4+i, col = bcol0+wc*32+n*16+lr
#pragma unroll
    for (int m = 0; m < 4; ++m) {
#pragma unroll
        for (int n = 0; n < 2; ++n) {
#pragma unroll
            for (int i = 0; i < 4; ++i) {
                int gr = brow0 + wr * 64 + m * 16 + lg * 4 + i;
                int gc = bcol0 + wc * 32 + n * 16 + lr;
                float v = acc[m][n][i];
                if (EPI == 1) {
                    out[(size_t)gr * 512 + gc] = v;
                } else {
                    int b = gr >> 11, in = gr & 2047;
                    if (gc < 512) {
                        int s = gc >> 6, d = gc & 63;
                        qs[((b * 8 + s) * 2048 + in) * 64 + d] = f2b(v * SCALE_L2E);
                    } else if (gc < 1024) {
                        int cgc = gc - 512; int s = cgc >> 6, d = cgc & 63;
                        ks[((b * 8 + s) * 2048 + in) * 64 + d] = f2b(v);
                    } else if (gc < 1152) {
                        int cgc = gc - 1024;             // 0..127 = r*64+d
                        vt[(b * 128 + cgc) * 2048 + in] = f2b(v);
                    } else {
                        int cgc = gc - 1152; int s = cgc >> 6, d = cgc & 63;
                        rqb[((b * 8 + s) * 2048 + in) * 64 + d] = f2b(v * SCALE_L2E);
                    }
                }
            }
        }
    }
}

// ---------------------------------------------------------------------------
// K2: flash attention (stage 1) + fused retrieval composition (stage 2).
// R9: manual unroll-by-2 (cur is a LITERAL in each body -> all LDS addresses
// fold to invariant base + offset immediates), incremental stage pointers
// (+=4096 / +=64 per tile instead of 64-bit recompute), s_setprio around
// MFMA clusters (T5). Structure otherwise identical to R7/R8.
// ---------------------------------------------------------------------------
__global__ __launch_bounds__(256, 2) void k_attn(const unsigned short* __restrict__ qs,
                                                 const unsigned short* __restrict__ ks,
                                                 const unsigned short* __restrict__ rqb,
                                                 const unsigned short* __restrict__ vt,
                                                 const unsigned short* __restrict__ wkt,
                                                 unsigned short* __restrict__ ob)
{
    // kbuf[2]: 2 x 8KB @ 0, 8192 ; vbuf[2]: 2 x 16KB @ 16384, 32768
    __shared__ unsigned char kv_lds[49152];
    __shared__ unsigned short p_lds[4][16][72];       // 9.2 KB (pad 64->72)

    const int tid = threadIdx.x;
    const int lane = tid & 63, wid = tid >> 6;
    const int lr = lane & 15, lg = lane >> 4;
    const int bid = blockIdx.x;
    const int bs = bid >> 5, qt = bid & 31;           // bs = b*8+s
    const int gb = bs >> 3, gs = bs & 7;
    const int qrow0 = qt * 64 + wid * 16;

    const int sub = lane >> 3;                        // 0..7 (row within 8-row stripe)
    const int chk = lane & 7;                         // 16B chunk slot
    const int scs = chk ^ sub;                        // swizzled source chunk
    const int swz = lr & 7;                           // read-side XOR

    // Q fragments, kept in registers for the whole main loop
    const unsigned short* qbase = qs + ((size_t)bs * 2048 + qrow0 + lr) * 64 + lg * 8;
    const bf16x8 q0 = *(const bf16x8*)(qbase);
    const bf16x8 q1 = *(const bf16x8*)(qbase + 32);

    const unsigned short* kbase = ks + (size_t)bs * 131072;     // [2048][64]
    const unsigned short* vbase = vt + (size_t)gb * 262144;     // [128][2048]

    const f32x4 z = {0.f, 0.f, 0.f, 0.f};
    bf16x8 ones;
#pragma unroll
    for (int j = 0; j < 8; ++j) ones[j] = (short)0x3F80;

    float m_r[4];
    f32x4 acc[8];
    f32x4 acc_l = z;
#pragma unroll
    for (int i = 0; i < 4; ++i) m_r[i] = -3.0e38f;
#pragma unroll
    for (int c8 = 0; c8 < 8; ++c8) acc[c8] = z;

    // --- incremental stage source pointers (per-lane, advanced per tile)
    const unsigned short* kst0 = kbase + (size_t)(wid * 16 + 0 + sub) * 64 + scs * 8;
    const unsigned short* kst1 = kbase + (size_t)(wid * 16 + 8 + sub) * 64 + scs * 8;
    const unsigned short* vst0 = vbase + (size_t)(wid * 32 +  0 + sub) * 2048 + scs * 8;
    const unsigned short* vst1 = vbase + (size_t)(wid * 32 +  8 + sub) * 2048 + scs * 8;
    const unsigned short* vst2 = vbase + (size_t)(wid * 32 + 16 + sub) * 2048 + scs * 8;
    const unsigned short* vst3 = vbase + (size_t)(wid * 32 + 24 + sub) * 2048 + scs * 8;

    auto STAGE = [&](const int buf) {
        unsigned char* kb = kv_lds + buf * 8192;
        unsigned char* vb = kv_lds + 16384 + buf * 16384;
        stage16(kst0, kb + (wid * 16 + 0) * 128);
        stage16(kst1, kb + (wid * 16 + 8) * 128);
        stage16(vst0, vb + (wid * 32 +  0) * 128);
        stage16(vst1, vb + (wid * 32 +  8) * 128);
        stage16(vst2, vb + (wid * 32 + 16) * 128);
        stage16(vst3, vb + (wid * 32 + 24) * 128);
        kst0 += 4096; kst1 += 4096;                   // 64 rows x 64 cols
        vst0 += 64; vst1 += 64; vst2 += 64; vst3 += 64;
    };

    auto COMPUTE = [&](const int cur) {
        const unsigned char* kb = kv_lds + cur * 8192;
        const unsigned char* vb = kv_lds + 16384 + cur * 16384;

        // --- S = Q K^T (16 x 64 tile) from LDS (swizzled reads)
        f32x4 s[4];
        __builtin_amdgcn_s_setprio(1);
#pragma unroll
        for (int ct = 0; ct < 4; ++ct) {
            const unsigned char* kr = kb + (ct * 16 + lr) * 128;
            bf16x8 kf0 = *(const bf16x8*)(kr + ((lg ^ swz) << 4));
            bf16x8 kf1 = *(const bf16x8*)(kr + (((lg + 4) ^ swz) << 4));
            f32x4 t = z;
            t = mfma16(q0, kf0, t);
            t = mfma16(q1, kf1, t);
            s[ct] = t;
        }
        __builtin_amdgcn_s_setprio(0);

        // --- deferred-max online softmax (log2 units)
        float lm[4];
        bool need = false;
#pragma unroll
        for (int i = 0; i < 4; ++i) {
            lm[i] = fmaxf(fmaxf(s[0][i], s[1][i]), fmaxf(s[2][i], s[3][i]));
            need = need || (lm[i] > m_r[i] + 8.0f);
        }
        if (__any(need)) {
#pragma unroll
            for (int i = 0; i < 4; ++i) {
                float mx = lm[i];
                mx = fmaxf(mx, __shfl_xor(mx, 1, 16));
                mx = fmaxf(mx, __shfl_xor(mx, 2, 16));
                mx = fmaxf(mx, __shfl_xor(mx, 4, 16));
                mx = fmaxf(mx, __shfl_xor(mx, 8, 16));
                float m_new = fmaxf(m_r[i], mx);
                float alpha = exp2f(m_r[i] - m_new);
#pragma unroll
                for (int c8 = 0; c8 < 8; ++c8) acc[c8][i] *= alpha;
                acc_l[i] *= alpha;
                m_r[i] = m_new;
            }
        }
        // --- P = exp2(S - m), bf16, through wave-private LDS tile
#pragma unroll
        for (int i = 0; i < 4; ++i) {
#pragma unroll
            for (int ct = 0; ct < 4; ++ct)
                p_lds[wid][lg * 4 + i][ct * 16 + lr] = f2b_hw(exp2f(s[ct][i] - m_r[i]));
        }
        bf16x8 pf0 = *(const bf16x8*)(&p_lds[wid][lr][lg * 8]);
        bf16x8 pf1 = *(const bf16x8*)(&p_lds[wid][lr][32 + lg * 8]);

        // --- PV from LDS V tile (+ row-sum via ones-column)
        __builtin_amdgcn_s_setprio(1);
#pragma unroll
        for (int c8 = 0; c8 < 8; ++c8) {
            const unsigned char* vr = vb + (c8 * 16 + lr) * 128;
            bf16x8 vf0 = *(const bf16x8*)(vr + ((lg ^ swz) << 4));
            bf16x8 vf1 = *(const bf16x8*)(vr + (((lg + 4) ^ swz) << 4));
            acc[c8] = mfma16(pf0, vf0, acc[c8]);
            acc[c8] = mfma16(pf1, vf1, acc[c8]);
        }
        acc_l = mfma16(pf0, ones, acc_l);
        acc_l = mfma16(pf1, ones, acc_l);
        __builtin_amdgcn_s_setprio(0);
    };

    STAGE(0);                                         // prologue: tile 0

    // tiles 0..29 in pairs (cur literal 0/1); stage always valid
#pragma unroll 1
    for (int it = 0; it < 15; ++it) {
        STAGE(1);
        asm volatile("s_waitcnt vmcnt(6)" ::: "memory");
        __syncthreads();
        COMPUTE(0);
        __syncthreads();

        STAGE(0);
        asm volatile("s_waitcnt vmcnt(6)" ::: "memory");
        __syncthreads();
        COMPUTE(1);
        __syncthreads();
    }
    // tile 30: stages tile 31
    STAGE(1);
    asm volatile("s_waitcnt vmcnt(6)" ::: "memory");
    __syncthreads();
    COMPUTE(0);
    __syncthreads();
    // tile 31: last, no stage
    asm volatile("s_waitcnt vmcnt(0)" ::: "memory");
    __syncthreads();
    COMPUTE(1);

    // --- epilogue: every wave holds full 2048-key state for its 16 rows
    float inv[4];
#pragma unroll
    for (int i = 0; i < 4; ++i) inv[i] = 1.0f / acc_l[i];

    // rq fragments (pre-scaled by DH^-0.5*log2e in k_proj)
    const unsigned short* rqbase = rqb + ((size_t)bs * 2048 + qrow0 + lr) * 64 + lg * 8;
    const bf16x8 rq0 = *(const bf16x8*)(rqbase);
    const bf16x8 rq1 = *(const bf16x8*)(rqbase + 32);

    // stage 2 via MFMA: T[q][d] = sum_dp rq[q][dp] * wk_ret[d][dp]
    f32x4 Tt[4];
#pragma unroll
    for (int ct = 0; ct < 4; ++ct) {
        bf16x8 wb0 = *(const bf16x8*)(wkt + (ct * 16 + lr) * 64 + lg * 8);
        bf16x8 wb1 = *(const bf16x8*)(wkt + (ct * 16 + lr) * 64 + 32 + lg * 8);
        f32x4 t = z;
        t = mfma16(rq0, wb0, t);
        t = mfma16(rq1, wb1, t);
        Tt[ct] = t;
    }

    // sim_r[row] = sum_{d} T[row][d] * retrN[row][r*64+d]   (log2 units)
    float w0v[4], w1v[4];
#pragma unroll
    for (int i = 0; i < 4; ++i) {
        float s0 = 0.f, s1 = 0.f;
#pragma unroll
        for (int ct = 0; ct < 4; ++ct) {
            s0 += Tt[ct][i] * acc[ct][i];
            s1 += Tt[ct][i] * acc[4 + ct][i];
        }
        s0 *= inv[i]; s1 *= inv[i];
        s0 += __shfl_xor(s0, 1, 16); s1 += __shfl_xor(s1, 1, 16);
        s0 += __shfl_xor(s0, 2, 16); s1 += __shfl_xor(s1, 2, 16);
        s0 += __shfl_xor(s0, 4, 16); s1 += __shfl_xor(s1, 4, 16);
        s0 += __shfl_xor(s0, 8, 16); s1 += __shfl_xor(s1, 8, 16);
        float mm = fmaxf(s0, s1);
        float e0 = exp2f(s0 - mm), e1 = exp2f(s1 - mm);
        float inw = 1.0f / (e0 + e1);
        w0v[i] = e0 * inw; w1v[i] = e1 * inw;
    }

    // --- combine r=2 and store ob[b][n][gs*64 + d]
#pragma unroll
    for (int ct = 0; ct < 4; ++ct) {
#pragma unroll
        for (int i = 0; i < 4; ++i) {
            float o = (w0v[i] * acc[ct][i] + w1v[i] * acc[4 + ct][i]) * inv[i];
            ob[((size_t)gb * 2048 + qrow0 + lg * 4 + i) * 512 + gs * 64 + ct * 16 + lr] = f2b_hw(o);
        }
    }
}

// ---------------------------------------------------------------------------
extern "C" void kernel_launch(void* const* d_in, const int* in_sizes, int n_in,
                              void* d_out, int out_size, void* d_ws, size_t ws_size,
                              hipStream_t stream)
{
    (void)in_sizes; (void)n_in; (void)out_size; (void)ws_size;
    const float* x      = (const float*)d_in[0];
    const float* wq_s   = (const float*)d_in[1];
    const float* wk_s   = (const float*)d_in[2];
    const float* wv_r   = (const float*)d_in[3];
    const float* wq_r   = (const float*)d_in[4];
    const float* wk_ret = (const float*)d_in[5];
    const float* w_out  = (const float*)d_in[6];

    char* ws = (char*)d_ws;                            // needs ~24.3 MB
    unsigned short* xb  = (unsigned short*)(ws + 0);          // [4096][512]
    unsigned short* wt  = (unsigned short*)(ws + 4194304);    // [1664][512]
    unsigned short* qsb = (unsigned short*)(ws + 5898240);    // [2][8][2048][64]
    unsigned short* ksb = (unsigned short*)(ws + 10092544);   // [2][8][2048][64]
    unsigned short* rqb = (unsigned short*)(ws + 14286848);   // [2][8][2048][64]
    unsigned short* vtb = (unsigned short*)(ws + 18481152);   // [2][128][2048]
    unsigned short* obb = (unsigned short*)(ws + 19529728);   // [2][2048][512]
    unsigned short* wot = (unsigned short*)(ws + 23724032);   // [512][512]
    unsigned short* wkt = (unsigned short*)(ws + 24248320);   // [64][64]

    hipLaunchKernelGGL(k_convert, dim3(2048), dim3(256), 0, stream,
                       x, wq_s, wk_s, wv_r, wq_r, wk_ret, w_out, xb, wt, wot, wkt);
    hipLaunchKernelGGL((k_gemm<0>), dim3(32, 26), dim3(256), 0, stream,
                       xb, wt, qsb, ksb, rqb, vtb, (float*)nullptr);
    hipLaunchKernelGGL(k_attn, dim3(512), dim3(256), 0, stream,
                       qsb, ksb, rqb, vtb, wkt, obb);
    hipLaunchKernelGGL((k_gemm<1>), dim3(32, 8), dim3(256), 0, stream,
                       obb, wot, (unsigned short*)nullptr, (unsigned short*)nullptr,
                       (unsigned short*)nullptr, (unsigned short*)nullptr, (float*)d_out);
}

// Round 10
// 95.669 us; speedup vs baseline: 4.4623x; 1.0073x over previous
//
#include <hip/hip_runtime.h>
#include <hip/hip_bf16.h>

#define DEV __device__ __forceinline__

typedef __attribute__((ext_vector_type(8))) short bf16x8;
typedef __attribute__((ext_vector_type(4))) float f32x4;

DEV float b2f(unsigned short u) {
    unsigned int v = ((unsigned int)u) << 16;
    float f; __builtin_memcpy(&f, &v, 4); return f;
}
DEV unsigned short f2b(float f) {            // RNE via bit-ops
    unsigned int v; __builtin_memcpy(&v, &f, 4);
    v = (v + 0x7fffu + ((v >> 16) & 1u)) >> 16;
    return (unsigned short)v;
}
DEV unsigned short f2b_hw(float f) {         // hardware cvt (RNE)
    __hip_bfloat16 h = __float2bfloat16(f);
    unsigned short u; __builtin_memcpy(&u, &h, 2); return u;
}

DEV f32x4 mfma16(bf16x8 a, bf16x8 b, f32x4 c) {
    return __builtin_amdgcn_mfma_f32_16x16x32_bf16(a, b, c, 0, 0, 0);
}

// global -> LDS async copy, 16B per lane; lds dest = uniform base + lane*16
DEV void stage16(const void* g, void* l) {
    __builtin_amdgcn_global_load_lds((const __attribute__((address_space(1))) void*)g,
                                     (__attribute__((address_space(3))) void*)l, 16, 0, 0);
}

#define WAIT_VM6()  asm volatile("s_waitcnt vmcnt(6)" ::: "memory")
#define WAIT_VM0()  asm volatile("s_waitcnt vmcnt(0)" ::: "memory")
#define WAIT_LGKM() asm volatile("s_waitcnt lgkmcnt(0)" ::: "memory")
#define BAR()       __builtin_amdgcn_s_barrier()
#define SCHED()     __builtin_amdgcn_sched_barrier(0)

constexpr float SCALE_L2E = 0.125f * 1.44269504088896340736f;  // DH^-0.5 * log2(e)

// ---------------------------------------------------------------------------
// K0: fp32 -> bf16 conversions.
//  xb[4096][512]  = x
//  wt[1664][512]  = [wq_s | wk_s | wv_r | wq_r]^T  (B^T form for MFMA)
//  wot[512][512]  = w_out^T
//  wkt[64][64]    = wk_ret ROW-MAJOR (B^T form for T = RQ @ wk_ret^T)
// ---------------------------------------------------------------------------
__global__ void k_convert(const float* __restrict__ x,
                          const float* __restrict__ wq_s, const float* __restrict__ wk_s,
                          const float* __restrict__ wv_r, const float* __restrict__ wq_r,
                          const float* __restrict__ wk_ret, const float* __restrict__ w_out,
                          unsigned short* __restrict__ xb,
                          unsigned short* __restrict__ wt,
                          unsigned short* __restrict__ wot,
                          unsigned short* __restrict__ wkt)
{
    const int T1 = 4096 * 512;
    const int T2 = 1664 * 512;
    const int T3 = 512 * 512;
    const int T4 = 64 * 64;
    const int total = T1 + T2 + T3 + T4;
    for (int idx = blockIdx.x * blockDim.x + threadIdx.x; idx < total;
         idx += gridDim.x * blockDim.x) {
        if (idx < T1) {
            xb[idx] = f2b(x[idx]);
        } else if (idx < T1 + T2) {
            int t = idx - T1;
            int n = t >> 9, k = t & 511;   // t == n*512 + k
            float v;
            if (n < 512)       v = wq_s[k * 512 + n];
            else if (n < 1024) v = wk_s[k * 512 + (n - 512)];
            else if (n < 1152) v = wv_r[k * 128 + (n - 1024)];
            else               v = wq_r[k * 512 + (n - 1152)];
            wt[t] = f2b(v);
        } else if (idx < T1 + T2 + T3) {
            int t = idx - T1 - T2;
            int n = t >> 9, k = t & 511;
            wot[t] = f2b(w_out[k * 512 + n]);
        } else {
            int t = idx - T1 - T2 - T3;
            wkt[t] = f2b(wk_ret[t]);       // identity copy (row-major B^T)
        }
    }
}

// ---------------------------------------------------------------------------
// K1/K3: staged GEMM  C[4096][N*] = A(bf16 [4096][512]) @ Bt(bf16 [N][512])^T
// BM=128, BN=64, BK=64; 4 waves 2x2, wave (wr,wc) owns 64x32 of C.
// R10: raw s_barrier + counted vmcnt — prefetch DMAs stay in flight across
// barriers (no __syncthreads vmcnt(0) drain).
// EPI=0: scatter epilogue into qs/ks/rqb/vt.  EPI=1: fp32 store epilogue.
// ---------------------------------------------------------------------------
template<int EPI>
__global__ __launch_bounds__(256, 2) void k_gemm(const unsigned short* __restrict__ A,
                                                 const unsigned short* __restrict__ Bt,
                                                 unsigned short* __restrict__ qs,
                                                 unsigned short* __restrict__ ks,
                                                 unsigned short* __restrict__ rqb,
                                                 unsigned short* __restrict__ vt,
                                                 float* __restrict__ out)
{
    // A bufs: 2 x 16KB @ 0,16384 ; B bufs: 2 x 8KB @ 32768,40960
    __shared__ unsigned char ab_lds[49152];

    const int tid = threadIdx.x;
    const int lane = tid & 63, wid = tid >> 6;
    const int lr = lane & 15, lg = lane >> 4;
    const int wr = wid >> 1, wc = wid & 1;
    const int brow0 = blockIdx.x * 128;
    const int bcol0 = blockIdx.y * 64;

    const int sub = lane >> 3;            // row within 8-row stripe
    const int chk = lane & 7;             // 16B chunk slot
    const int scs = chk ^ sub;            // swizzled source chunk

    const f32x4 z = {0.f, 0.f, 0.f, 0.f};
    f32x4 acc[4][2];
#pragma unroll
    for (int m = 0; m < 4; ++m)
#pragma unroll
        for (int n = 0; n < 2; ++n) acc[m][n] = z;

    const unsigned short* Ab = A + (size_t)brow0 * 512;

    auto STAGE = [&](int buf, int k0) {
        unsigned char* ab = ab_lds + buf * 16384;
        unsigned char* bb = ab_lds + 32768 + buf * 8192;
#pragma unroll
        for (int ii = 0; ii < 4; ++ii) {
            int r0 = wid * 32 + ii * 8;
            const unsigned short* g = Ab + (size_t)(r0 + sub) * 512 + k0 + scs * 8;
            stage16(g, ab + r0 * 128);
        }
#pragma unroll
        for (int ii = 0; ii < 2; ++ii) {
            int r0 = wid * 16 + ii * 8;
            const unsigned short* g = Bt + (size_t)(bcol0 + r0 + sub) * 512 + k0 + scs * 8;
            stage16(g, bb + r0 * 128);
        }
    };

    auto COMPUTE = [&](const int cur) {
        const unsigned char* ab = ab_lds + cur * 16384;
        const unsigned char* bb = ab_lds + 32768 + cur * 8192;
#pragma unroll
        for (int ksb = 0; ksb < 2; ++ksb) {
            const int c = ksb * 4 + lg;                       // k-chunk 0..7
            bf16x8 bfr[2];
#pragma unroll
            for (int n = 0; n < 2; ++n) {
                int row = wc * 32 + n * 16 + lr;
                bfr[n] = *(const bf16x8*)(bb + row * 128 + ((c ^ (row & 7)) << 4));
            }
#pragma unroll
            for (int m = 0; m < 4; ++m) {
                int row = wr * 64 + m * 16 + lr;
                bf16x8 af = *(const bf16x8*)(ab + row * 128 + ((c ^ (row & 7)) << 4));
                acc[m][0] = mfma16(af, bfr[0], acc[m][0]);
                acc[m][1] = mfma16(af, bfr[1], acc[m][1]);
            }
        }
    };

    STAGE(0, 0);
#pragma unroll 1
    for (int it = 0; it < 3; ++it) {
        STAGE(1, (2 * it + 1) * 64);
        WAIT_VM6(); BAR(); SCHED();
        COMPUTE(0);
        WAIT_LGKM(); SCHED(); BAR(); SCHED();
        STAGE(0, (2 * it + 2) * 64);
        WAIT_VM6(); BAR(); SCHED();
        COMPUTE(1);
        WAIT_LGKM(); SCHED(); BAR(); SCHED();
    }
    STAGE(1, 7 * 64);
    WAIT_VM6(); BAR(); SCHED();
    COMPUTE(0);                                   // tile 6
    WAIT_LGKM(); SCHED(); BAR(); SCHED();
    WAIT_VM0(); BAR(); SCHED();
    COMPUTE(1);                                   // tile 7

    // --- epilogue: C row = brow0+wr*64+m*16+lg*4+i, col = bcol0+wc*32+n*16+lr
#pragma unroll
    for (int m = 0; m < 4; ++m) {
#pragma unroll
        for (int n = 0; n < 2; ++n) {
#pragma unroll
            for (int i = 0; i < 4; ++i) {
                int gr = brow0 + wr * 64 + m * 16 + lg * 4 + i;
                int gc = bcol0 + wc * 32 + n * 16 + lr;
                float v = acc[m][n][i];
                if (EPI == 1) {
                    out[(size_t)gr * 512 + gc] = v;
                } else {
                    int b = gr >> 11, in = gr & 2047;
                    if (gc < 512) {
                        int s = gc >> 6, d = gc & 63;
                        qs[((b * 8 + s) * 2048 + in) * 64 + d] = f2b(v * SCALE_L2E);
                    } else if (gc < 1024) {
                        int cgc = gc - 512; int s = cgc >> 6, d = cgc & 63;
                        ks[((b * 8 + s) * 2048 + in) * 64 + d] = f2b(v);
                    } else if (gc < 1152) {
                        int cgc = gc - 1024;             // 0..127 = r*64+d
                        vt[(b * 128 + cgc) * 2048 + in] = f2b(v);
                    } else {
                        int cgc = gc - 1152; int s = cgc >> 6, d = cgc & 63;
                        rqb[((b * 8 + s) * 2048 + in) * 64 + d] = f2b(v * SCALE_L2E);
                    }
                }
            }
        }
    }
}

// ---------------------------------------------------------------------------
// K2: flash attention (stage 1) + fused retrieval composition (stage 2).
// R10: raw s_barrier + counted vmcnt(6) — the 6 prefetch DMAs for tile t+1
// stay in flight across both barriers and land during COMPUTE(t). Per-wave
// vmcnt is sound: each wave waits only for ITS OWN 6 stage loads; barrier
// makes the union (= whole tile) visible. lgkmcnt(0)+barrier protects the
// buffer from being restaged while any wave still reads it.
// ---------------------------------------------------------------------------
__global__ __launch_bounds__(256, 2) void k_attn(const unsigned short* __restrict__ qs,
                                                 const unsigned short* __restrict__ ks,
                                                 const unsigned short* __restrict__ rqb,
                                                 const unsigned short* __restrict__ vt,
                                                 const unsigned short* __restrict__ wkt,
                                                 unsigned short* __restrict__ ob)
{
    // kbuf[2]: 2 x 8KB @ 0, 8192 ; vbuf[2]: 2 x 16KB @ 16384, 32768
    __shared__ unsigned char kv_lds[49152];
    __shared__ unsigned short p_lds[4][16][72];       // 9.2 KB (pad 64->72)

    const int tid = threadIdx.x;
    const int lane = tid & 63, wid = tid >> 6;
    const int lr = lane & 15, lg = lane >> 4;
    const int bid = blockIdx.x;
    const int bs = bid >> 5, qt = bid & 31;           // bs = b*8+s
    const int gb = bs >> 3, gs = bs & 7;
    const int qrow0 = qt * 64 + wid * 16;

    const int sub = lane >> 3;                        // 0..7 (row within 8-row stripe)
    const int chk = lane & 7;                         // 16B chunk slot
    const int scs = chk ^ sub;                        // swizzled source chunk
    const int swz = lr & 7;                           // read-side XOR

    // Q fragments, kept in registers for the whole main loop
    const unsigned short* qbase = qs + ((size_t)bs * 2048 + qrow0 + lr) * 64 + lg * 8;
    const bf16x8 q0 = *(const bf16x8*)(qbase);
    const bf16x8 q1 = *(const bf16x8*)(qbase + 32);

    const unsigned short* kbase = ks + (size_t)bs * 131072;     // [2048][64]
    const unsigned short* vbase = vt + (size_t)gb * 262144;     // [128][2048]

    const f32x4 z = {0.f, 0.f, 0.f, 0.f};
    bf16x8 ones;
#pragma unroll
    for (int j = 0; j < 8; ++j) ones[j] = (short)0x3F80;

    float m_r[4];
    f32x4 acc[8];
    f32x4 acc_l = z;
#pragma unroll
    for (int i = 0; i < 4; ++i) m_r[i] = -3.0e38f;
#pragma unroll
    for (int c8 = 0; c8 < 8; ++c8) acc[c8] = z;

    // --- incremental stage source pointers (per-lane, advanced per tile)
    const unsigned short* kst0 = kbase + (size_t)(wid * 16 + 0 + sub) * 64 + scs * 8;
    const unsigned short* kst1 = kbase + (size_t)(wid * 16 + 8 + sub) * 64 + scs * 8;
    const unsigned short* vst0 = vbase + (size_t)(wid * 32 +  0 + sub) * 2048 + scs * 8;
    const unsigned short* vst1 = vbase + (size_t)(wid * 32 +  8 + sub) * 2048 + scs * 8;
    const unsigned short* vst2 = vbase + (size_t)(wid * 32 + 16 + sub) * 2048 + scs * 8;
    const unsigned short* vst3 = vbase + (size_t)(wid * 32 + 24 + sub) * 2048 + scs * 8;

    auto STAGE = [&](const int buf) {
        unsigned char* kb = kv_lds + buf * 8192;
        unsigned char* vb = kv_lds + 16384 + buf * 16384;
        stage16(kst0, kb + (wid * 16 + 0) * 128);
        stage16(kst1, kb + (wid * 16 + 8) * 128);
        stage16(vst0, vb + (wid * 32 +  0) * 128);
        stage16(vst1, vb + (wid * 32 +  8) * 128);
        stage16(vst2, vb + (wid * 32 + 16) * 128);
        stage16(vst3, vb + (wid * 32 + 24) * 128);
        kst0 += 4096; kst1 += 4096;                   // 64 rows x 64 cols
        vst0 += 64; vst1 += 64; vst2 += 64; vst3 += 64;
    };

    auto COMPUTE = [&](const int cur) {
        const unsigned char* kb = kv_lds + cur * 8192;
        const unsigned char* vb = kv_lds + 16384 + cur * 16384;

        // --- S = Q K^T (16 x 64 tile) from LDS (swizzled reads)
        f32x4 s[4];
        __builtin_amdgcn_s_setprio(1);
#pragma unroll
        for (int ct = 0; ct < 4; ++ct) {
            const unsigned char* kr = kb + (ct * 16 + lr) * 128;
            bf16x8 kf0 = *(const bf16x8*)(kr + ((lg ^ swz) << 4));
            bf16x8 kf1 = *(const bf16x8*)(kr + (((lg + 4) ^ swz) << 4));
            f32x4 t = z;
            t = mfma16(q0, kf0, t);
            t = mfma16(q1, kf1, t);
            s[ct] = t;
        }
        __builtin_amdgcn_s_setprio(0);

        // --- deferred-max online softmax (log2 units)
        float lm[4];
        bool need = false;
#pragma unroll
        for (int i = 0; i < 4; ++i) {
            lm[i] = fmaxf(fmaxf(s[0][i], s[1][i]), fmaxf(s[2][i], s[3][i]));
            need = need || (lm[i] > m_r[i] + 8.0f);
        }
        if (__any(need)) {
#pragma unroll
            for (int i = 0; i < 4; ++i) {
                float mx = lm[i];
                mx = fmaxf(mx, __shfl_xor(mx, 1, 16));
                mx = fmaxf(mx, __shfl_xor(mx, 2, 16));
                mx = fmaxf(mx, __shfl_xor(mx, 4, 16));
                mx = fmaxf(mx, __shfl_xor(mx, 8, 16));
                float m_new = fmaxf(m_r[i], mx);
                float alpha = exp2f(m_r[i] - m_new);
#pragma unroll
                for (int c8 = 0; c8 < 8; ++c8) acc[c8][i] *= alpha;
                acc_l[i] *= alpha;
                m_r[i] = m_new;
            }
        }
        // --- P = exp2(S - m), bf16, through wave-private LDS tile
#pragma unroll
        for (int i = 0; i < 4; ++i) {
#pragma unroll
            for (int ct = 0; ct < 4; ++ct)
                p_lds[wid][lg * 4 + i][ct * 16 + lr] = f2b_hw(exp2f(s[ct][i] - m_r[i]));
        }
        bf16x8 pf0 = *(const bf16x8*)(&p_lds[wid][lr][lg * 8]);
        bf16x8 pf1 = *(const bf16x8*)(&p_lds[wid][lr][32 + lg * 8]);

        // --- PV from LDS V tile (+ row-sum via ones-column)
        __builtin_amdgcn_s_setprio(1);
#pragma unroll
        for (int c8 = 0; c8 < 8; ++c8) {
            const unsigned char* vr = vb + (c8 * 16 + lr) * 128;
            bf16x8 vf0 = *(const bf16x8*)(vr + ((lg ^ swz) << 4));
            bf16x8 vf1 = *(const bf16x8*)(vr + (((lg + 4) ^ swz) << 4));
            acc[c8] = mfma16(pf0, vf0, acc[c8]);
            acc[c8] = mfma16(pf1, vf1, acc[c8]);
        }
        acc_l = mfma16(pf0, ones, acc_l);
        acc_l = mfma16(pf1, ones, acc_l);
        __builtin_amdgcn_s_setprio(0);
    };

    STAGE(0);                                         // tile 0 -> buf0

    // tiles 0..29 in pairs (cur literal 0/1); 6 prefetch DMAs ride across
    // barriers (counted vmcnt, never drained to 0 in the steady state)
#pragma unroll 1
    for (int it = 0; it < 15; ++it) {
        STAGE(1);                                     // tile 2it+1
        WAIT_VM6(); BAR(); SCHED();
        COMPUTE(0);                                   // tile 2it
        WAIT_LGKM(); SCHED(); BAR(); SCHED();
        STAGE(0);                                     // tile 2it+2
        WAIT_VM6(); BAR(); SCHED();
        COMPUTE(1);                                   // tile 2it+1
        WAIT_LGKM(); SCHED(); BAR(); SCHED();
    }
    STAGE(1);                                         // tile 31
    WAIT_VM6(); BAR(); SCHED();
    COMPUTE(0);                                       // tile 30
    WAIT_LGKM(); SCHED(); BAR(); SCHED();
    WAIT_VM0(); BAR(); SCHED();
    COMPUTE(1);                                       // tile 31

    // --- epilogue: every wave holds full 2048-key state for its 16 rows
    float inv[4];
#pragma unroll
    for (int i = 0; i < 4; ++i) inv[i] = 1.0f / acc_l[i];

    // rq fragments (pre-scaled by DH^-0.5*log2e in k_gemm<0>)
    const unsigned short* rqbase = rqb + ((size_t)bs * 2048 + qrow0 + lr) * 64 + lg * 8;
    const bf16x8 rq0 = *(const bf16x8*)(rqbase);
    const bf16x8 rq1 = *(const bf16x8*)(rqbase + 32);

    // stage 2 via MFMA: T[q][d] = sum_dp rq[q][dp] * wk_ret[d][dp]
    f32x4 Tt[4];
#pragma unroll
    for (int ct = 0; ct < 4; ++ct) {
        bf16x8 wb0 = *(const bf16x8*)(wkt + (ct * 16 + lr) * 64 + lg * 8);
        bf16x8 wb1 = *(const bf16x8*)(wkt + (ct * 16 + lr) * 64 + 32 + lg * 8);
        f32x4 t = z;
        t = mfma16(rq0, wb0, t);
        t = mfma16(rq1, wb1, t);
        Tt[ct] = t;
    }

    // sim_r[row] = sum_{d} T[row][d] * retrN[row][r*64+d]   (log2 units)
    float w0v[4], w1v[4];
#pragma unroll
    for (int i = 0; i < 4; ++i) {
        float s0 = 0.f, s1 = 0.f;
#pragma unroll
        for (int ct = 0; ct < 4; ++ct) {
            s0 += Tt[ct][i] * acc[ct][i];
            s1 += Tt[ct][i] * acc[4 + ct][i];
        }
        s0 *= inv[i]; s1 *= inv[i];
        s0 += __shfl_xor(s0, 1, 16); s1 += __shfl_xor(s1, 1, 16);
        s0 += __shfl_xor(s0, 2, 16); s1 += __shfl_xor(s1, 2, 16);
        s0 += __shfl_xor(s0, 4, 16); s1 += __shfl_xor(s1, 4, 16);
        s0 += __shfl_xor(s0, 8, 16); s1 += __shfl_xor(s1, 8, 16);
        float mm = fmaxf(s0, s1);
        float e0 = exp2f(s0 - mm), e1 = exp2f(s1 - mm);
        float inw = 1.0f / (e0 + e1);
        w0v[i] = e0 * inw; w1v[i] = e1 * inw;
    }

    // --- combine r=2 and store ob[b][n][gs*64 + d]
#pragma unroll
    for (int ct = 0; ct < 4; ++ct) {
#pragma unroll
        for (int i = 0; i < 4; ++i) {
            float o = (w0v[i] * acc[ct][i] + w1v[i] * acc[4 + ct][i]) * inv[i];
            ob[((size_t)gb * 2048 + qrow0 + lg * 4 + i) * 512 + gs * 64 + ct * 16 + lr] = f2b_hw(o);
        }
    }
}

// ---------------------------------------------------------------------------
extern "C" void kernel_launch(void* const* d_in, const int* in_sizes, int n_in,
                              void* d_out, int out_size, void* d_ws, size_t ws_size,
                              hipStream_t stream)
{
    (void)in_sizes; (void)n_in; (void)out_size; (void)ws_size;
    const float* x      = (const float*)d_in[0];
    const float* wq_s   = (const float*)d_in[1];
    const float* wk_s   = (const float*)d_in[2];
    const float* wv_r   = (const float*)d_in[3];
    const float* wq_r   = (const float*)d_in[4];
    const float* wk_ret = (const float*)d_in[5];
    const float* w_out  = (const float*)d_in[6];

    char* ws = (char*)d_ws;                            // needs ~24.3 MB
    unsigned short* xb  = (unsigned short*)(ws + 0);          // [4096][512]
    unsigned short* wt  = (unsigned short*)(ws + 4194304);    // [1664][512]
    unsigned short* qsb = (unsigned short*)(ws + 5898240);    // [2][8][2048][64]
    unsigned short* ksb = (unsigned short*)(ws + 10092544);   // [2][8][2048][64]
    unsigned short* rqb = (unsigned short*)(ws + 14286848);   // [2][8][2048][64]
    unsigned short* vtb = (unsigned short*)(ws + 18481152);   // [2][128][2048]
    unsigned short* obb = (unsigned short*)(ws + 19529728);   // [2][2048][512]
    unsigned short* wot = (unsigned short*)(ws + 23724032);   // [512][512]
    unsigned short* wkt = (unsigned short*)(ws + 24248320);   // [64][64]

    hipLaunchKernelGGL(k_convert, dim3(2048), dim3(256), 0, stream,
                       x, wq_s, wk_s, wv_r, wq_r, wk_ret, w_out, xb, wt, wot, wkt);
    hipLaunchKernelGGL((k_gemm<0>), dim3(32, 26), dim3(256), 0, stream,
                       xb, wt, qsb, ksb, rqb, vtb, (float*)nullptr);
    hipLaunchKernelGGL(k_attn, dim3(512), dim3(256), 0, stream,
                       qsb, ksb, rqb, vtb, wkt, obb);
    hipLaunchKernelGGL((k_gemm<1>), dim3(32, 8), dim3(256), 0, stream,
                       obb, wot, (unsigned short*)nullptr, (unsigned short*)nullptr,
                       (unsigned short*)nullptr, (unsigned short*)nullptr, (float*)d_out);
}